// Round 12
// baseline (2577.440 us; speedup 1.0000x reference)
//
#include <hip/hip_runtime.h>
#include <math.h>

#define B_ 8
#define S_ 2
#define L_ 32000
#define T_ 497
#define AE 256
#define NFREQ 129
#define FC 385
#define XSTR 388
#define FRSTR 516
#define AFSTR 516
#define BTL 256
#define H_ 512
#define NB 32
#define EMBED 20
#define KB (T_*FC)
#define MEPS 1e-12f
#define PI2F 6.28318530717958647692f
#define MTOT (B_*T_)
#define SEPN 7700
#define SEPNT16 484   /* ceil(7700/16)=482 -> pad to 484 so 64-col tiles (121) divide evenly */
#define SEPBLK 7623   /* 121*63 */

typedef __attribute__((ext_vector_type(8))) short bf16x8;
typedef __attribute__((ext_vector_type(4))) float f32x4;

__device__ __forceinline__ ushort f2bf(float f){
  union { float f; unsigned u; } x; x.f = f;
  unsigned r = x.u + 0x7FFFu + ((x.u >> 16) & 1u);
  return (ushort)(r >> 16);
}
__device__ __forceinline__ float bf2f(ushort h){
  union { unsigned u; float f; } x; x.u = ((unsigned)h) << 16;
  return x.f;
}

// atomic-point load (bypasses L1 and scalar cache; sees device-scope atomicAdd)
__device__ __forceinline__ float aldf(const float* p){
  return __hip_atomic_load(p, __ATOMIC_RELAXED, __HIP_MEMORY_SCOPE_AGENT);
}

// ---------------- workspace layout (float units) ----------------
static constexpr size_t ALGN(size_t x){ return (x + 63) & ~(size_t)63; }
static constexpr size_t o_bfr  = 0;                                   // 256*516
static constexpr size_t o_decB = ALGN(o_bfr + (size_t)256*516);       // 514*256
static constexpr size_t o_decBias = ALGN(o_decB + (size_t)514*256);   // 256
static constexpr size_t o_biasF  = ALGN(o_decBias + 256);             // 516
static constexpr size_t o_cf   = ALGN(o_biasF + 516);                 // 3976*516
static constexpr size_t o_mag  = ALGN(o_cf + (size_t)B_*T_*FRSTR);
static constexpr size_t o_cosp = ALGN(o_mag + (size_t)B_*T_*NFREQ);
static constexpr size_t o_sinp = ALGN(o_cosp + (size_t)B_*T_*NFREQ);
static constexpr size_t o_xln  = ALGN(o_sinp + (size_t)B_*T_*NFREQ); // xln; later xb16 (bf16 x_final)
static constexpr size_t o_x    = ALGN(o_xln + (size_t)B_*T_*XSTR);   // x buf0 (3976*256)
static constexpr size_t o_y    = ALGN(o_x + (size_t)B_*T_*BTL);      // x buf1 + U  (2*3976*256) ; later framesp
static constexpr size_t o_z    = ALGN(o_y + (size_t)B_*T_*H_);       // yb16 (bf16 3976*512 + pad)
static constexpr size_t o_gsum = ALGN(o_z + (size_t)B_*T_*H_);       // 32*32
static constexpr size_t o_acc  = o_gsum + 1024;                      // B*16*21
static constexpr size_t o_att  = ALGN(o_acc + (size_t)B_*16*21);
static constexpr size_t o_emb  = ALGN(o_att + (size_t)B_*2*EMBED);
static constexpr size_t o_Af   = ALGN(o_emb + (size_t)B_*KB*EMBED);  // 7952*516; earlier: packed sep_w bf16
static constexpr size_t o_w1p  = ALGN(o_Af + (size_t)2*B_*T_*AFSTR); // 32*131072 ush
static constexpr size_t o_w2p  = ALGN(o_w1p + (size_t)2097152);
static constexpr size_t o_c1c2 = ALGN(o_w2p + (size_t)2097152);      // 32*512
static constexpr size_t o_bar  = ALGN(o_c1c2 + (size_t)32*512);      // grid-barrier state (1024 f)
static constexpr size_t o_fr   = o_y;

#define PREP_BLOCKS 1034
#define PACKW_BLOCKS 32768
#define BIAS2_BLOCKS 256
#define PACKSEP_BLOCKS 7744   /* 8*484*64*8 / 256 */

// ---------------- merged setup: bases/biases + weight packing + bias2 fold ---
__global__ __launch_bounds__(256) void k_setup(
    const float* __restrict__ enc_w, const float* __restrict__ enc_b,
    const float* __restrict__ dec_w, const float* __restrict__ dec_b,
    const float* __restrict__ c1_w, const float* __restrict__ c2_w,
    const float* __restrict__ g2_g, const float* __restrict__ g2_b,
    const float* __restrict__ sep_w,
    float* __restrict__ bfr, float* __restrict__ decB,
    float* __restrict__ decBias, float* __restrict__ biasF,
    ushort* __restrict__ w1p, ushort* __restrict__ w2p,
    float* __restrict__ c1c2, ushort* __restrict__ w3p)
{
  int bx = blockIdx.x;
  if (bx < PREP_BLOCKS){
    int i = bx*256 + threadIdx.x;
    if (i < 256*516){
      int k = i / 516, n = i % 516;
      float v;
      if (n < 256) v = enc_w[(size_t)k*256 + n];
      else if (n < 514){
        int f2 = n - 256;
        float win = sqrtf(0.5f - 0.5f*cosf(PI2F * (float)k / 256.0f));
        int f = (f2 < NFREQ) ? f2 : (f2 - NFREQ);
        int m = (k * f) & 255;
        float th = PI2F * (float)m / 256.0f;
        v = (f2 < NFREQ) ? win * cosf(th) : -win * sinf(th);
      } else v = 0.f;
      bfr[i] = v;
      return;
    }
    int j = i - 256*516;
    if (j < 514*256){
      int k = j / 256, n = j & 255;
      float v;
      if (k < 256){
        v = 0.5f * dec_w[(size_t)k*256 + n];
      } else {
        int m = n & 63;
        float den = 0.f;
        #pragma unroll
        for (int q = 0; q < 4; q++) den += 0.5f - 0.5f*cosf(PI2F*(float)(m + 64*q)/256.0f);
        float win = sqrtf(0.5f - 0.5f*cosf(PI2F*(float)n/256.0f));
        float iw = win / den;
        int f = (k < 385) ? (k - 256) : (k - 385);
        int mm = (f * n) & 255;
        float th = PI2F * (float)mm / 256.0f;
        if (k < 385){
          float cf = (f==0 || f==128) ? 1.0f : 2.0f;
          v = 0.5f * iw * cf * cosf(th) * (1.0f/256.0f);
        } else {
          v = (f==0 || f==128) ? 0.0f : -1.0f * iw * sinf(th) * (1.0f/256.0f);
        }
      }
      decB[j] = v;
      return;
    }
    int jj = j - 514*256;
    if (jj < 256){ decBias[jj] = 0.5f * dec_b[jj]; return; }
    int n = jj - 256;
    if (n < 516) biasF[n] = (n < 256) ? enc_b[n] : 0.f;
    return;
  }
  if (bx < PREP_BLOCKS + PACKW_BLOCKS){
    size_t idx = (size_t)(bx - PREP_BLOCKS)*256 + threadIdx.x;
    const size_t PER = (size_t)32*131072;
    if (idx < PER){
      int i = (int)(idx >> 17);
      int o = (int)(idx & 131071);
      int kc = o >> 14;
      int n16 = (o >> 9) & 31;
      int l = (o >> 3) & 63;
      int j = o & 7;
      int k = kc*32 + (l>>4)*8 + j;
      int n = n16*16 + (l&15);
      w1p[idx] = f2bf(c1_w[((size_t)i*256 + k)*512 + n]);
    } else {
      size_t o2 = idx - PER;
      int i = (int)(o2 >> 17);
      int o = (int)(o2 & 131071);
      int kc = o >> 13;
      int n16 = (o >> 9) & 15;
      int l = (o >> 3) & 63;
      int j = o & 7;
      int k = kc*32 + (l>>4)*8 + j;
      int n = n16*16 + (l&15);
      w2p[o2] = f2bf(g2_g[(size_t)i*512 + k] * c2_w[((size_t)i*512 + k)*256 + n]);
    }
    return;
  }
  if (bx < PREP_BLOCKS + PACKW_BLOCKS + BIAS2_BLOCKS){
    // bias2 fold: block (layer i, k-slab ks); 8-way atomic accumulation
    int bi = bx - (PREP_BLOCKS + PACKW_BLOCKS);
    int i = bi >> 3, ks = bi & 7;
    int n = threadIdx.x;
    float s1 = 0.f, s2 = 0.f;
    for (int k = ks*64; k < ks*64 + 64; k++){
      float w = c2_w[((size_t)i*512 + k)*256 + n];
      s1 = fmaf(g2_b[(size_t)i*512 + k], w, s1);
      s2 = fmaf(g2_g[(size_t)i*512 + k], w, s2);
    }
    atomicAdd(&c1c2[(size_t)i*512 + n], s1);
    atomicAdd(&c1c2[(size_t)i*512 + 256 + n], s2);
    return;
  }
  // pack sep_w -> bf16 MFMA B-fragment layout, N padded 7700 -> 7744
  {
    size_t idx = (size_t)(bx - (PREP_BLOCKS + PACKW_BLOCKS + BIAS2_BLOCKS))*256 + threadIdx.x;
    int j = (int)(idx & 7);
    int l = (int)((idx >> 3) & 63);
    int rest = (int)(idx >> 9);
    int n16 = rest % SEPNT16;
    int kc = rest / SEPNT16;
    int k = kc*32 + (l>>4)*8 + j;
    int n = n16*16 + (l&15);
    w3p[idx] = (n < SEPN) ? f2bf(sep_w[(size_t)k*SEPN + n]) : (ushort)0;
  }
}

// ---------------- pipelined 64x64 GEMM (non-TCN) ----------------
template<int ALOAD>
__global__ __launch_bounds__(256, 2) void gemm3(
    const float* __restrict__ A, const float* __restrict__ Bm,
    const float* __restrict__ bias, float* __restrict__ C,
    int M, int N, int K, int lda, int ldb, int relu_cols)
{
  __shared__ float As[16][68];
  __shared__ float Bs[16][68];
  const int tid = threadIdx.x;
  const int tx = tid & 15, ty = tid >> 4;
  const int row0 = blockIdx.y*64, col0 = blockIdx.x*64;
  const int am = tid >> 2, ak = (tid & 3)*4;
  const int bk = tid >> 4, bn = (tid & 15)*4;
  const int arow = row0 + am;
  const bool aok = arow < M;
  const float* aptr = nullptr;
  const float* ap0 = nullptr; const float* ap1 = nullptr;
  if (ALOAD == 2){
    int r = aok ? arow : 0;
    int b = r / T_, t = r % T_;
    ap0 = A + ((size_t)b*2)*L_ + t*64;
    ap1 = ap0 + L_;
  } else {
    aptr = A + (size_t)(aok ? arow : 0)*lda;
  }
  const bool bfull = (col0 + 64 <= N);
  const int ksteps = (K+15) >> 4;

  float4 av, bv;

#define LOADA(ks_) { int k0 = (ks_) << 4; \
    av = make_float4(0.f,0.f,0.f,0.f); \
    if (aok){ \
      if (ALOAD == 2){ \
        float4 u = *(const float4*)(ap0 + k0 + ak); \
        float4 w = *(const float4*)(ap1 + k0 + ak); \
        av.x = u.x+w.x; av.y = u.y+w.y; av.z = u.z+w.z; av.w = u.w+w.w; \
      } else if (k0 + ak + 4 <= lda){ \
        av = *(const float4*)(aptr + k0 + ak); \
      } else { \
        float* pv = (float*)&av; \
        for (int j = 0; j < 4; j++){ int k = k0+ak+j; if (k < K) pv[j] = aptr[k]; } \
      } \
    } }

#define LOADB(ks_) { int k = ((ks_) << 4) + bk; \
    bv = make_float4(0.f,0.f,0.f,0.f); \
    if (k < K){ \
      if (bfull) bv = *(const float4*)(Bm + (size_t)k*ldb + col0 + bn); \
      else { float* pv = (float*)&bv; \
        for (int j = 0; j < 4; j++){ int c = col0+bn+j; if (c < N) pv[j] = Bm[(size_t)k*ldb + c]; } } } }

  float acc[4][4] = {};
  LOADA(0); LOADB(0);
  for (int ks = 0; ks < ksteps; ks++){
    As[ak+0][am] = av.x; As[ak+1][am] = av.y;
    As[ak+2][am] = av.z; As[ak+3][am] = av.w;
    *(float4*)&Bs[bk][bn] = bv;
    __syncthreads();
    if (ks + 1 < ksteps){ LOADA(ks+1); LOADB(ks+1); }
    #pragma unroll
    for (int kk = 0; kk < 16; kk++){
      float a4[4], b4[4];
      *(float4*)a4 = *(const float4*)&As[kk][ty*4];
      *(float4*)b4 = *(const float4*)&Bs[kk][tx*4];
      #pragma unroll
      for (int i = 0; i < 4; i++)
        #pragma unroll
        for (int j = 0; j < 4; j++) acc[i][j] = fmaf(a4[i], b4[j], acc[i][j]);
    }
    __syncthreads();
  }
#undef LOADA
#undef LOADB

  float bb4[4];
  #pragma unroll
  for (int j = 0; j < 4; j++){
    int c = col0 + tx*4 + j;
    bb4[j] = (bias && c < N) ? bias[c] : 0.f;
  }
  #pragma unroll
  for (int i = 0; i < 4; i++){
    int r_l = row0 + ty*4 + i;
    if (r_l >= M) continue;
    size_t r_g = (size_t)r_l;
    int c0 = col0 + tx*4;
    if (bfull){
      float4 o; float* po = (float*)&o;
      #pragma unroll
      for (int j = 0; j < 4; j++){
        float v = acc[i][j] + bb4[j];
        if (c0 + j < relu_cols) v = fmaxf(v, 0.f);
        po[j] = v;
      }
      *(float4*)(C + r_g*N + c0) = o;
    } else {
      #pragma unroll
      for (int j = 0; j < 4; j++){
        int c = c0 + j;
        if (c >= N) continue;
        float v = acc[i][j] + bb4[j];
        if (c < relu_cols) v = fmaxf(v, 0.f);
        C[r_g*N + c] = v;
      }
    }
  }
}

// ---------------- separator: bf16 MFMA GEMM, M=3976 N=7700(pad 7744) K=256 ---
__global__ __launch_bounds__(256, 2) void k_sep(
    const ushort* __restrict__ xb, const ushort* __restrict__ wp,
    const float* __restrict__ bias, float* __restrict__ C)
{
  int id = blockIdx.x;
  int xcd = id & 7, sub = id >> 3;
  const int q = SEPBLK/8, r = SEPBLK%8;   // 952, 7 — bijective chunked map
  int lin = (xcd < r ? xcd*(q+1) : r*(q+1) + (xcd - r)*q) + sub;
  int nb = lin/63, mt = lin%63;
  int tid = threadIdx.x;
  int wv = tid >> 6, l = tid & 63;
  int row0 = mt*64 + wv*16;
  int lm = l & 15, lq = l >> 4;
  int row = row0 + lm;
  int rclamp = (row < MTOT) ? row : (MTOT-1);
  int n0 = nb*64;
  const ushort* ap = xb + (size_t)rclamp*256;
  f32x4 acc[4] = {};
  #pragma unroll
  for (int kc = 0; kc < 8; kc++){
    bf16x8 a = *(const bf16x8*)(ap + kc*32 + lq*8);
    #pragma unroll
    for (int nt = 0; nt < 4; nt++){
      bf16x8 bfv = *(const bf16x8*)(wp + (((size_t)kc*SEPNT16 + (n0>>4) + nt)*64 + l)*8);
      acc[nt] = __builtin_amdgcn_mfma_f32_16x16x32_bf16(a, bfv, acc[nt], 0, 0, 0);
    }
  }
  #pragma unroll
  for (int nt = 0; nt < 4; nt++){
    int col = n0 + nt*16 + lm;
    if (col >= SEPN) continue;
    float bb = bias[col];
    #pragma unroll
    for (int r2 = 0; r2 < 4; r2++){
      int t = row0 + lq*4 + r2;
      if (t < MTOT) C[(size_t)t*SEPN + col] = acc[nt][r2] + bb;
    }
  }
}

// ---- per-batch barrier (64 blocks/group), same-XCD L2 protocol (R7) ----
__device__ __forceinline__ void pbar(unsigned* bar, int grp){
  __syncthreads();   // compiler emits s_waitcnt vmcnt(0) before s_barrier -> stores in L2
  if (threadIdx.x == 0){
    unsigned* g = bar + grp*64;
    unsigned gen = __hip_atomic_load(g+32, __ATOMIC_RELAXED, __HIP_MEMORY_SCOPE_AGENT);
    unsigned p = gen & 1u;
    unsigned a = __hip_atomic_fetch_add(g+p, 1u, __ATOMIC_RELAXED, __HIP_MEMORY_SCOPE_AGENT);
    if (a == 63u){
      __hip_atomic_store(g+p, 0u, __ATOMIC_RELAXED, __HIP_MEMORY_SCOPE_AGENT);
      __hip_atomic_store(g+32, gen+1u, __ATOMIC_RELAXED, __HIP_MEMORY_SCOPE_AGENT);
    } else {
      while (__hip_atomic_load(g+32, __ATOMIC_RELAXED, __HIP_MEMORY_SCOPE_AGENT) == gen)
        __builtin_amdgcn_s_sleep(1);
    }
    asm volatile("buffer_inv sc0" ::: "memory");
  }
  __syncthreads();
}

// ================= fused persistent TCN (normal launch, graph-safe) ========
// R12: same 512-block grid / nb=8 decomposition (traffic sweet spot) but
// 512-thread blocks: waves 0-3 = four 16-row groups with kc-half 0, waves
// 4-7 = same rows kc-half 1; partial MFMA accs combined via LDS. Total
// per-block loads are the old ones partitioned -> traffic IDENTICAL, but
// waves/SIMD 2->4 (2x latency hiding; R9's occupancy attempt paid 2x traffic,
// this one is free). LDS-staged constants (R11) + NT weights + R7 L2
// protocol retained.
__global__ __launch_bounds__(512, 4) void k_tcn(
    float* __restrict__ x0, float* __restrict__ x1,
    float* __restrict__ Ubuf, ushort* __restrict__ yb,
    const ushort* __restrict__ w1pA, const ushort* __restrict__ w2pA,
    const float* __restrict__ c1bA, const float* __restrict__ p1A,
    const float* __restrict__ g1gA, const float* __restrict__ g1bA,
    const float* __restrict__ dwA, const float* __restrict__ p2A,
    const float* __restrict__ c2bA, const float* __restrict__ ccA,
    float* __restrict__ gsum, unsigned* bar)
{
  __shared__ float red[16];
  __shared__ float cst[3072];   // constants: B: ga|ba|dw0|dw1|dw2|pa (6x512); A: addv (256)
  __shared__ float swp[4096];   // kc-half accumulator swap (A: 4x64x16, B: 4x64x8)
  const int tid = threadIdx.x;
  const int wv = tid >> 6, l = tid & 63;
  const int rowgrp = wv & 3, kchalf = wv >> 2;
  const int bid = blockIdx.x;
  const int b = bid & 7, mt = (bid >> 3) & 7, nb = bid >> 6;
  const int row0 = mt*64 + rowgrp*16;
  const int lm = l & 15, lq = l >> 4;
  const int row = row0 + lm;
  const bool rok = row < T_;
  const size_t rbase = ((size_t)b*T_ + row)*256;
  const float icnt = 1.f/((float)T_*(float)H_);

  for (int i = 0; i < NB; i++){
    // ---------------- phase A (kc-half split) ----------------
    {
      const float* xr = (i == 0) ? x0 : (((i-1)&1) ? x1 : x0);
      float* xw = (i & 1) ? x1 : x0;
      const ushort* w1p = w1pA + (size_t)i*131072;
      const float* bias = c1bA + (size_t)i*H_;
      const float* pa   = p1A + (size_t)i*H_;
      float* gs = gsum + i*32;
      const int hasU = (i > 0) ? 1 : 0;
      const float* c2bPrev = c2bA + (size_t)((i > 0) ? (i-1) : 0)*BTL;
      const float* ccPrev  = ccA  + (size_t)((i > 0) ? (i-1) : 0)*512;
      const float* gsPrev  = (i == 0) ? gsum : (gsum + (i-1)*32 + 16);

      float rstd2 = 0.f;
      if (hasU){
        float m2 = aldf(gsPrev + b*2)*icnt;
        rstd2 = rsqrtf(aldf(gsPrev + b*2 + 1)*icnt - m2*m2 + MEPS);
        float mr = m2*rstd2;
        if (tid < 256) cst[tid] = c2bPrev[tid] + ccPrev[tid] - mr*ccPrev[256 + tid];
      }
      __syncthreads();
      int n0 = nb*64;
      f32x4 acc[4] = {};
      #pragma unroll
      for (int kci = 0; kci < 4; kci++){
        int kc = kchalf*4 + kci;
        int k0 = kc*32 + lq*8;
        float xv[8];
        *(float4*)&xv[0] = *(const float4*)(xr + rbase + k0);
        *(float4*)&xv[4] = *(const float4*)(xr + rbase + k0 + 4);
        if (hasU){
          float uv[8], av8[8];
          *(float4*)&uv[0]  = *(const float4*)(Ubuf + rbase + k0);
          *(float4*)&uv[4]  = *(const float4*)(Ubuf + rbase + k0 + 4);
          *(float4*)&av8[0] = *(float4*)&cst[k0];
          *(float4*)&av8[4] = *(float4*)&cst[k0 + 4];
          #pragma unroll
          for (int j = 0; j < 8; j++)
            xv[j] = xv[j] + rstd2*uv[j] + av8[j];
          if (nb == 0 && rok){
            *(float4*)(xw + rbase + k0)     = *(float4*)&xv[0];
            *(float4*)(xw + rbase + k0 + 4) = *(float4*)&xv[4];
          }
        }
        bf16x8 a;
        #pragma unroll
        for (int j = 0; j < 8; j++) a[j] = (short)f2bf(xv[j]);
        #pragma unroll
        for (int nt = 0; nt < 4; nt++){
          bf16x8 bf = __builtin_nontemporal_load(
              (const bf16x8*)(w1p + (((size_t)kc*32 + (n0>>4) + nt)*64 + l)*8));
          acc[nt] = __builtin_amdgcn_mfma_f32_16x16x32_bf16(a, bf, acc[nt], 0, 0, 0);
        }
      }
      // combine kc-halves via LDS
      if (kchalf == 1){
        #pragma unroll
        for (int nt = 0; nt < 4; nt++)
          *(f32x4*)&swp[(((size_t)rowgrp*64 + l)*4 + nt)*4] = acc[nt];
      }
      __syncthreads();
      float ps = 0.f, pss = 0.f;
      if (kchalf == 0){
        #pragma unroll
        for (int nt = 0; nt < 4; nt++){
          f32x4 o = *(f32x4*)&swp[(((size_t)rowgrp*64 + l)*4 + nt)*4];
          acc[nt][0] += o[0]; acc[nt][1] += o[1];
          acc[nt][2] += o[2]; acc[nt][3] += o[3];
        }
        #pragma unroll
        for (int nt = 0; nt < 4; nt++){
          int col = n0 + nt*16 + lm;
          float bb = bias[col], pav = pa[col];
          #pragma unroll
          for (int r = 0; r < 4; r++){
            int t = row0 + lq*4 + r;
            if (t < T_){
              float v = acc[nt][r] + bb;
              float p = fmaxf(v, 0.f) + pav*fminf(v, 0.f);
              yb[((size_t)b*T_ + t)*512 + col] = f2bf(p);
              ps += p; pss += p*p;
            }
          }
        }
      }
      #pragma unroll
      for (int off = 32; off > 0; off >>= 1){
        ps  += __shfl_down(ps, off);
        pss += __shfl_down(pss, off);
      }
      if (l == 0 && kchalf == 0){ red[rowgrp*2] = ps; red[rowgrp*2+1] = pss; }
      __syncthreads();
      if (tid == 0) atomicAdd(&gs[b*2],   red[0]+red[2]+red[4]+red[6]);
      if (tid == 1) atomicAdd(&gs[b*2+1], red[1]+red[3]+red[5]+red[7]);
    }
    pbar(bar, b);
    // ---------------- phase B (kc-half split) ----------------
    {
      const int dil = 1 << (i & 7);
      const ushort* w2p = w2pA + (size_t)i*131072;
      const float* dwk = dwA + (size_t)i*3*H_;
      const float* gg  = g1gA + (size_t)i*H_;
      const float* gb  = g1bA + (size_t)i*H_;
      const float* pa  = p2A + (size_t)i*H_;
      const float* gs1 = gsum + i*32;
      float* gs2 = gsum + i*32 + 16;

      float m1 = aldf(gs1 + b*2)*icnt;
      float rstd1 = rsqrtf(aldf(gs1 + b*2 + 1)*icnt - m1*m1 + MEPS);
      // stage folded constants: ga | ba | dw0 | dw1 | dw2 | pa  (6 x 512)
      {
        int c = tid;
        float ga_ = gg[c]*rstd1;
        cst[c]        = ga_;
        cst[512 + c]  = gb[c] - m1*ga_;
        cst[1024 + c] = dwk[c];
        cst[1536 + c] = dwk[H_ + c];
        cst[2048 + c] = dwk[2*H_ + c];
        cst[2560 + c] = pa[c];
      }
      __syncthreads();
      int n0 = nb*32;
      f32x4 acc[2] = {};
      float sp = 0.f, spp = 0.f;
      const bool dostat = (nb == 0) && rok;
      #pragma unroll
      for (int kci = 0; kci < 8; kci++){
        int kc = kchalf*8 + kci;
        int ch0 = kc*32 + lq*8;
        float ga8[8], ba8[8];
        *(float4*)&ga8[0] = *(float4*)&cst[ch0];
        *(float4*)&ga8[4] = *(float4*)&cst[ch0 + 4];
        *(float4*)&ba8[0] = *(float4*)&cst[512 + ch0];
        *(float4*)&ba8[4] = *(float4*)&cst[512 + ch0 + 4];
        float z[8] = {0.f,0.f,0.f,0.f,0.f,0.f,0.f,0.f};
        #pragma unroll
        for (int kk = 0; kk < 3; kk++){
          int tt = row + (kk-1)*dil;
          if (tt >= 0 && tt < T_){
            bf16x8 yv = *(const bf16x8*)(yb + ((size_t)b*T_ + tt)*512 + ch0);
            float d8[8];
            *(float4*)&d8[0] = *(float4*)&cst[1024 + kk*512 + ch0];
            *(float4*)&d8[4] = *(float4*)&cst[1024 + kk*512 + ch0 + 4];
            #pragma unroll
            for (int j = 0; j < 8; j++)
              z[j] = fmaf(d8[j], bf2f((ushort)yv[j])*ga8[j] + ba8[j], z[j]);
          }
        }
        float pa8[8];
        *(float4*)&pa8[0] = *(float4*)&cst[2560 + ch0];
        *(float4*)&pa8[4] = *(float4*)&cst[2560 + ch0 + 4];
        bf16x8 a;
        #pragma unroll
        for (int j = 0; j < 8; j++){
          float p = fmaxf(z[j], 0.f) + pa8[j]*fminf(z[j], 0.f);
          if (dostat){ sp += p; spp += p*p; }
          a[j] = (short)f2bf(p);
        }
        #pragma unroll
        for (int nt = 0; nt < 2; nt++){
          bf16x8 bf = __builtin_nontemporal_load(
              (const bf16x8*)(w2p + (((size_t)kc*16 + (n0>>4) + nt)*64 + l)*8));
          acc[nt] = __builtin_amdgcn_mfma_f32_16x16x32_bf16(a, bf, acc[nt], 0, 0, 0);
        }
      }
      // combine kc-halves via LDS
      if (kchalf == 1){
        #pragma unroll
        for (int nt = 0; nt < 2; nt++)
          *(f32x4*)&swp[(((size_t)rowgrp*64 + l)*2 + nt)*4] = acc[nt];
      }
      __syncthreads();
      if (kchalf == 0){
        #pragma unroll
        for (int nt = 0; nt < 2; nt++){
          f32x4 o = *(f32x4*)&swp[(((size_t)rowgrp*64 + l)*2 + nt)*4];
          acc[nt][0] += o[0]; acc[nt][1] += o[1];
          acc[nt][2] += o[2]; acc[nt][3] += o[3];
        }
        #pragma unroll
        for (int nt = 0; nt < 2; nt++){
          int col = n0 + nt*16 + lm;
          #pragma unroll
          for (int r = 0; r < 4; r++){
            int tr = row0 + lq*4 + r;
            if (tr < T_) Ubuf[((size_t)b*T_ + tr)*256 + col] = acc[nt][r];
          }
        }
      }
      if (nb == 0){
        #pragma unroll
        for (int off = 32; off > 0; off >>= 1){
          sp  += __shfl_down(sp, off);
          spp += __shfl_down(spp, off);
        }
        if (l == 0){ red[wv*2] = sp; red[wv*2+1] = spp; }
        __syncthreads();
        if (tid == 0) atomicAdd(&gs2[b*2],
          red[0]+red[2]+red[4]+red[6]+red[8]+red[10]+red[12]+red[14]);
        if (tid == 1) atomicAdd(&gs2[b*2+1],
          red[1]+red[3]+red[5]+red[7]+red[9]+red[11]+red[13]+red[15]);
      }
    }
    if (i < NB-1) pbar(bar, b);
  }
}

// final deferred apply after layer 31 — writes x_final directly as bf16
__global__ __launch_bounds__(256) void k_applyx(
    const float* __restrict__ xr, const float* __restrict__ U,
    const float* __restrict__ gs, const float* __restrict__ c2b,
    const float* __restrict__ cc, ushort* __restrict__ xo)
{
  int i = blockIdx.x*256 + threadIdx.x;
  if (i < B_*T_*256){
    int b = i / (T_*256);
    int k = i & 255;
    const float icnt = 1.f/((float)T_*(float)H_);
    float m = gs[b*2]*icnt;
    float rstd = rsqrtf(gs[b*2+1]*icnt - m*m + MEPS);
    float mr = m*rstd;
    xo[i] = f2bf(xr[i] + rstd*U[i] + c2b[k] + cc[k] - mr*cc[256 + k]);
  }
}

// ---------------- cLN over [enc | log1p(mag)] ----------------
__global__ __launch_bounds__(256) void k_cln(
    const float* __restrict__ cf,
    const float* __restrict__ gamma, const float* __restrict__ beta,
    float* __restrict__ mag, float* __restrict__ cosp, float* __restrict__ sinp,
    float* __restrict__ xln){
  int t = blockIdx.x, b = blockIdx.y, tid = threadIdx.x;
  size_t row = (size_t)b*T_ + t;
  __shared__ float feat[FC];
  __shared__ float red[8];
  feat[tid] = cf[row*FRSTR + tid];
  if (tid < NFREQ){
    float re = cf[row*FRSTR + 256 + tid], im = cf[row*FRSTR + 385 + tid];
    float m = sqrtf(re*re + im*im);
    mag[row*NFREQ + tid] = m;
    float c = 1.f, s = 0.f;
    if (m > 0.f){ c = re/m; s = im/m; }
    cosp[row*NFREQ + tid] = c;
    sinp[row*NFREQ + tid] = s;
    feat[AE + tid] = log1pf(m);
  }
  __syncthreads();
  float v = feat[tid] + ((tid < FC-256) ? feat[256+tid] : 0.f);
  #pragma unroll
  for (int off = 32; off > 0; off >>= 1) v += __shfl_down(v, off);
  if ((tid & 63) == 0) red[tid>>6] = v;
  __syncthreads();
  float mean = (red[0]+red[1]+red[2]+red[3]) * (1.0f/FC);
  float d0 = feat[tid] - mean;
  float vv = d0*d0;
  if (tid < FC-256){ float d1 = feat[256+tid] - mean; vv += d1*d1; }
  __syncthreads();
  #pragma unroll
  for (int off = 32; off > 0; off >>= 1) vv += __shfl_down(vv, off);
  if ((tid & 63) == 0) red[tid>>6] = vv;
  __syncthreads();
  float var = (red[0]+red[1]+red[2]+red[3]) * (1.0f/FC);
  float rstd = rsqrtf(var + MEPS);
  xln[row*XSTR + tid] = (feat[tid]-mean)*rstd*gamma[tid] + beta[tid];
  if (tid < FC-256)
    xln[row*XSTR + 256+tid] = (feat[256+tid]-mean)*rstd*gamma[256+tid] + beta[256+tid];
  if (tid < XSTR-FC) xln[row*XSTR + FC + tid] = 0.f;
}

// ---------------- attractor accumulation ------------
#define ATTR_CH 16
__global__ __launch_bounds__(256) void k_attr2(const float* __restrict__ emb,
                                               const float* __restrict__ anchors,
                                               float* __restrict__ acc){
  const int c0a[16] = {0,0,0,0,0,1,1,1,1,2,2,2,3,3,4,0};
  const int c1a[16] = {1,2,3,4,5,2,3,4,5,3,4,5,4,5,5,0};
  int by = blockIdx.y;
  int b = by >> 2, g = by & 3;
  int tid = threadIdx.x;
  __shared__ float anc[6][20];
  __shared__ float wred[4][84];
  if (tid < 120) anc[tid/20][tid%20] = anchors[tid];
  __syncthreads();
  float ar[4][21];
  #pragma unroll
  for (int q = 0; q < 4; q++)
    #pragma unroll
    for (int e = 0; e < 21; e++) ar[q][e] = 0.f;
  const float* eb = emb + (size_t)b*KB*EMBED;
  for (int k = blockIdx.x*256 + tid; k < KB; k += ATTR_CH*256){
    float e[20];
    const float4* p = (const float4*)(eb + (size_t)k*EMBED);
    #pragma unroll
    for (int i = 0; i < 5; i++){
      float4 v = p[i];
      e[4*i] = v.x; e[4*i+1] = v.y; e[4*i+2] = v.z; e[4*i+3] = v.w;
    }
    float d[6];
    #pragma unroll
    for (int c = 0; c < 6; c++){
      float s = 0.f;
      #pragma unroll
      for (int j = 0; j < 20; j++) s = fmaf(e[j], anc[c][j], s);
      d[c] = s;
    }
    #pragma unroll
    for (int q = 0; q < 4; q++){
      int s = g*4 + q;
      float w = (s == 15) ? 1.0f : 1.0f / (1.0f + expf(d[c1a[s]] - d[c0a[s]]));
      #pragma unroll
      for (int j = 0; j < 20; j++) ar[q][j] = fmaf(w, e[j], ar[q][j]);
      ar[q][20] += w;
    }
  }
  #pragma unroll
  for (int q = 0; q < 4; q++)
    #pragma unroll
    for (int e = 0; e < 21; e++)
      #pragma unroll
      for (int off = 32; off > 0; off >>= 1)
        ar[q][e] += __shfl_down(ar[q][e], off);
  if ((tid & 63) == 0){
    int w = tid >> 6;
    #pragma unroll
    for (int q = 0; q < 4; q++)
      #pragma unroll
      for (int e = 0; e < 21; e++) wred[w][q*21+e] = ar[q][e];
  }
  __syncthreads();
  if (tid < 84){
    float s = wred[0][tid] + wred[1][tid] + wred[2][tid] + wred[3][tid];
    int q = tid / 21, e = tid % 21;
    atomicAdd(&acc[((size_t)b*16 + g*4 + q)*21 + e], s);
  }
}

// ---------------- attractor normalize + select ----------------
__global__ __launch_bounds__(128) void k_attrfin2(const float* __restrict__ acc,
                                                  float* __restrict__ attractors){
  __shared__ float aN[120][40];
  __shared__ float sp[120];
  int tid = threadIdx.x;
  if (tid < 120){
    int b = tid / 15, p = tid % 15;
    const float* ap = acc + ((size_t)b*16 + p)*21;
    const float* ae = acc + ((size_t)b*16 + 15)*21;
    float den0 = ap[20];
    float den1 = (float)KB - den0;
    float s = 0.f;
    for (int e = 0; e < 20; e++){
      float a0 = ap[e] / den0;
      float a1 = (ae[e] - ap[e]) / den1;
      aN[tid][e] = a0; aN[tid][20+e] = a1;
      s = fmaf(a0, a1, s);
    }
    sp[tid] = s;
  }
  __syncthreads();
  if (tid < B_){
    int base = tid * 15, best = 0;
    float bv = sp[base];
    for (int p = 1; p < 15; p++) if (sp[base+p] < bv){ bv = sp[base+p]; best = p; }
    for (int i = 0; i < 40; i++) attractors[tid*40 + i] = aN[base+best][i];
  }
}

// ---------------- build decoder-GEMM A rows (stride 516, pads zeroed) -------
__global__ __launch_bounds__(256) void k_afull(
    const float* __restrict__ emb, const float* __restrict__ cf,
    const float* __restrict__ mag, const float* __restrict__ cosp,
    const float* __restrict__ sinp, const float* __restrict__ attractors,
    float* __restrict__ Af){
  int t = blockIdx.x, b = blockIdx.y, tid = threadIdx.x;
  __shared__ float att[40];
  if (tid < 40) att[tid] = attractors[b*40 + tid];
  __syncthreads();
  size_t row = (size_t)b*T_ + t;
  size_t r0 = ((size_t)(b*2+0)*T_ + t)*AFSTR;
  size_t r1 = ((size_t)(b*2+1)*T_ + t)*AFSTR;
  for (int f = tid; f < FC; f += 256){
    const float* e = emb + (row*FC + f)*20;
    float l0 = 0.f, l1 = 0.f;
    #pragma unroll
    for (int j = 0; j < 20; j++){
      float ev = e[j];
      l0 = fmaf(ev, att[j],    l0);
      l1 = fmaf(ev, att[20+j], l1);
    }
    if (f < AE){
      float ft = cf[row*FRSTR + f];
      Af[r0 + f] = l0*ft;
      Af[r1 + f] = l1*ft;
    } else {
      int fi = f - AE;
      float ft = mag[row*NFREQ + fi];
      float c = cosp[row*NFREQ + fi], s = sinp[row*NFREQ + fi];
      float s0 = l0*ft, s1v = l1*ft;
      Af[r0 + 256 + fi] = c*s0;  Af[r0 + 385 + fi] = s*s0;
      Af[r1 + 256 + fi] = c*s1v; Af[r1 + 385 + fi] = s*s1v;
    }
  }
  if (tid < 2){
    Af[r0 + 514 + tid] = 0.f;
    Af[r1 + 514 + tid] = 0.f;
  }
}

// ---------------- overlap-add gather ----------------
__global__ __launch_bounds__(256) void k_ola(const float* __restrict__ frames,
                                             float* __restrict__ out){
  int i = blockIdx.x*256 + threadIdx.x;
  if (i < B_*2*L_){
    int bs = i / L_, l = i % L_;
    int t0 = l >> 6;
    float s = 0.f;
    #pragma unroll
    for (int j = 0; j < 4; j++){
      int t = t0 - j;
      if (t >= 0 && t < T_){
        int k = l - t*64;
        s += frames[((size_t)bs*T_ + t)*256 + k];
      }
    }
    out[i] = s;
  }
}

// ---------------- launcher ----------------
extern "C" void kernel_launch(void* const* d_in, const int* in_sizes, int n_in,
                              void* d_out, int out_size, void* d_ws, size_t ws_size,
                              hipStream_t stream) {
  const float* audios   = (const float*)d_in[0];
  const float* enc_w    = (const float*)d_in[1];
  const float* enc_b    = (const float*)d_in[2];
  const float* bgamma   = (const float*)d_in[3];
  const float* bbeta    = (const float*)d_in[4];
  const float* bottle_w = (const float*)d_in[5];
  const float* bottle_b = (const float*)d_in[6];
  const float* c1_w     = (const float*)d_in[7];
  const float* c1_b     = (const float*)d_in[8];
  const float* p1       = (const float*)d_in[9];
  const float* g1_g     = (const float*)d_in[10];
  const float* g1_b     = (const float*)d_in[11];
  const float* dwp      = (const float*)d_in[12];
  const float* p2       = (const float*)d_in[13];
  const float* g2_g     = (const float*)d_in[14];
  const float* g2_b     = (const float*)d_in[15];
  const float* c2_w     = (const float*)d_in[16];
  const float* c2_b     = (const float*)d_in[17];
  const float* sep_w    = (const float*)d_in[18];
  const float* sep_b    = (const float*)d_in[19];
  const float* anchors  = (const float*)d_in[20];
  const float* dec_w    = (const float*)d_in[21];
  const float* dec_b    = (const float*)d_in[22];

  float* ws = (float*)d_ws;
  float* bfr   = ws + o_bfr;
  float* decB  = ws + o_decB;
  float* decBias = ws + o_decBias;
  float* biasF = ws + o_biasF;
  float* cf    = ws + o_cf;
  float* mag   = ws + o_mag;
  float* cosp  = ws + o_cosp;
  float* sinp  = ws + o_sinp;
  float* xln   = ws + o_xln;
  float* xbuf0 = ws + o_x;
  float* xbuf1 = ws + o_y;                         // first half of o_y region
  float* Ubuf  = ws + o_y + (size_t)B_*T_*BTL;     // second half
  float* gsum  = ws + o_gsum;
  float* accp  = ws + o_acc;
  float* attp  = ws + o_att;
  float* embp  = ws + o_emb;
  float* Afull = ws + o_Af;
  float* framesp = ws + o_fr;
  float* c1c2  = ws + o_c1c2;
  unsigned* barp = (unsigned*)(ws + o_bar);
  ushort* w1p  = (ushort*)(ws + o_w1p);
  ushort* w2p  = (ushort*)(ws + o_w2p);
  ushort* w3p  = (ushort*)(ws + o_Af);   // packed sep_w bf16; dead before k_afull writes Af
  ushort* xb16 = (ushort*)(ws + o_xln);  // bf16 x_final; xln dead after bottleneck GEMM
  ushort* yb16 = (ushort*)(ws + o_z);

  // zero atomic accumulators (gsum 1024 + attr acc 2688, contiguous), c1c2, barrier
  hipMemsetAsync((void*)gsum, 0, (1024 + (size_t)B_*16*21) * sizeof(float), stream);
  hipMemsetAsync((void*)c1c2, 0, (size_t)32*512*sizeof(float), stream);
  hipMemsetAsync((void*)barp, 0, 1024*sizeof(float), stream);

  k_setup<<<PREP_BLOCKS + PACKW_BLOCKS + BIAS2_BLOCKS + PACKSEP_BLOCKS, 256, 0, stream>>>(
      enc_w, enc_b, dec_w, dec_b, c1_w, c2_w, g2_g, g2_b, sep_w,
      bfr, decB, decBias, biasF, w1p, w2p, c1c2, w3p);

  // frames GEMM: mix-on-load, [enc | spec] out, M=3976, N=516, K=256
  gemm3<2><<<dim3(9, 63), 256, 0, stream>>>(
      audios, bfr, biasF, cf, B_*T_, FRSTR, 256, 0, FRSTR, 256);

  k_cln<<<dim3(T_, B_), 256, 0, stream>>>(cf, bgamma, bbeta, mag, cosp, sinp, xln);

  // bottleneck -> x(0) in buf0
  gemm3<0><<<dim3(4, 63), 256, 0, stream>>>(
      xln, bottle_w, bottle_b, xbuf0, B_*T_, BTL, FC, XSTR, BTL, 0);

  // TCN: single persistent kernel, 512 blocks x 512 thr (kc-split waves)
  k_tcn<<<dim3(512), dim3(512), 0, stream>>>(
      xbuf0, xbuf1, Ubuf, yb16, w1p, w2p,
      c1_b, p1, g1_g, g1_b, dwp, p2, c2_b, c1c2, gsum, barp);

  // final apply: x_final = x(31) + rstd2*U(31) + cadd(31) -> bf16 xb16 (x(31) in buf1)
  k_applyx<<<(B_*T_*256 + 255)/256, 256, 0, stream>>>(
      xbuf1, Ubuf, gsum + (NB-1)*32 + 16,
      c2_b + (size_t)(NB-1)*BTL, c1c2 + (size_t)(NB-1)*512, xb16);

  // separator (bf16 MFMA): M=3976, N=7700 (pad 7744), K=256; XCD-chunked
  k_sep<<<dim3(SEPBLK), 256, 0, stream>>>(xb16, w3p, sep_b, embp);

  // attractors
  k_attr2<<<dim3(ATTR_CH, B_*4), 256, 0, stream>>>(embp, anchors, accp);
  k_attrfin2<<<1, 128, 0, stream>>>(accp, attp);

  // decode: M=7952, N=256, K=514 (lda=516, zero-padded)
  k_afull<<<dim3(T_, B_), 256, 0, stream>>>(embp, cf, mag, cosp, sinp, attp, Afull);
  gemm3<0><<<dim3(4, 125), 256, 0, stream>>>(
      Afull, decB, decBias, framesp, 2*B_*T_, 256, 514, AFSTR, BTL, 0);
  k_ola<<<(B_*2*L_ + 255)/256, 256, 0, stream>>>(framesp, (float*)d_out);
}

// Round 13
// 1750.561 us; speedup vs baseline: 1.4724x; 1.4724x over previous
//
#include <hip/hip_runtime.h>
#include <math.h>

#define B_ 8
#define S_ 2
#define L_ 32000
#define T_ 497
#define AE 256
#define NFREQ 129
#define FC 385
#define XSTR 388
#define FRSTR 516
#define AFSTR 516
#define BTL 256
#define H_ 512
#define NB 32
#define EMBED 20
#define KB (T_*FC)
#define MEPS 1e-12f
#define PI2F 6.28318530717958647692f
#define MTOT (B_*T_)
#define SEPN 7700
#define SEPNT16 484   /* ceil(7700/16)=482 -> pad to 484 so 64-col tiles (121) divide evenly */
#define SEPBLK 7623   /* 121*63 */

typedef __attribute__((ext_vector_type(8))) short bf16x8;
typedef __attribute__((ext_vector_type(4))) float f32x4;

__device__ __forceinline__ ushort f2bf(float f){
  union { float f; unsigned u; } x; x.f = f;
  unsigned r = x.u + 0x7FFFu + ((x.u >> 16) & 1u);
  return (ushort)(r >> 16);
}
__device__ __forceinline__ float bf2f(ushort h){
  union { unsigned u; float f; } x; x.u = ((unsigned)h) << 16;
  return x.f;
}

// atomic-point load (bypasses L1 and scalar cache; sees device-scope atomicAdd)
__device__ __forceinline__ float aldf(const float* p){
  return __hip_atomic_load(p, __ATOMIC_RELAXED, __HIP_MEMORY_SCOPE_AGENT);
}

// ---------------- workspace layout (float units) ----------------
static constexpr size_t ALGN(size_t x){ return (x + 63) & ~(size_t)63; }
static constexpr size_t o_bfr  = 0;                                   // 256*516
static constexpr size_t o_decB = ALGN(o_bfr + (size_t)256*516);       // 514*256
static constexpr size_t o_decBias = ALGN(o_decB + (size_t)514*256);   // 256
static constexpr size_t o_biasF  = ALGN(o_decBias + 256);             // 516
static constexpr size_t o_cf   = ALGN(o_biasF + 516);                 // 3976*516
static constexpr size_t o_mag  = ALGN(o_cf + (size_t)B_*T_*FRSTR);
static constexpr size_t o_cosp = ALGN(o_mag + (size_t)B_*T_*NFREQ);
static constexpr size_t o_sinp = ALGN(o_cosp + (size_t)B_*T_*NFREQ);
static constexpr size_t o_xln  = ALGN(o_sinp + (size_t)B_*T_*NFREQ); // xln; later xb16 (bf16 x_final)
static constexpr size_t o_x    = ALGN(o_xln + (size_t)B_*T_*XSTR);   // x buf0 (3976*256)
static constexpr size_t o_y    = ALGN(o_x + (size_t)B_*T_*BTL);      // x buf1 + U  (2*3976*256) ; later framesp
static constexpr size_t o_z    = ALGN(o_y + (size_t)B_*T_*H_);       // yb16 (bf16 3976*512 + pad)
static constexpr size_t o_gsum = ALGN(o_z + (size_t)B_*T_*H_);       // 32*32
static constexpr size_t o_acc  = o_gsum + 1024;                      // B*16*21
static constexpr size_t o_att  = ALGN(o_acc + (size_t)B_*16*21);
static constexpr size_t o_emb  = ALGN(o_att + (size_t)B_*2*EMBED);
static constexpr size_t o_Af   = ALGN(o_emb + (size_t)B_*KB*EMBED);  // 7952*516; earlier: packed sep_w bf16
static constexpr size_t o_w1p  = ALGN(o_Af + (size_t)2*B_*T_*AFSTR); // 32*131072 ush
static constexpr size_t o_w2p  = ALGN(o_w1p + (size_t)2097152);
static constexpr size_t o_c1c2 = ALGN(o_w2p + (size_t)2097152);      // 32*512
static constexpr size_t o_bar  = ALGN(o_c1c2 + (size_t)32*512);      // grid-barrier state (1024 f)
static constexpr size_t o_fr   = o_y;

#define PREP_BLOCKS 1034
#define PACKW_BLOCKS 32768
#define BIAS2_BLOCKS 256
#define PACKSEP_BLOCKS 7744   /* 8*484*64*8 / 256 */

// ---------------- merged setup: bases/biases + weight packing + bias2 fold ---
__global__ __launch_bounds__(256) void k_setup(
    const float* __restrict__ enc_w, const float* __restrict__ enc_b,
    const float* __restrict__ dec_w, const float* __restrict__ dec_b,
    const float* __restrict__ c1_w, const float* __restrict__ c2_w,
    const float* __restrict__ g2_g, const float* __restrict__ g2_b,
    const float* __restrict__ sep_w,
    float* __restrict__ bfr, float* __restrict__ decB,
    float* __restrict__ decBias, float* __restrict__ biasF,
    ushort* __restrict__ w1p, ushort* __restrict__ w2p,
    float* __restrict__ c1c2, ushort* __restrict__ w3p)
{
  int bx = blockIdx.x;
  if (bx < PREP_BLOCKS){
    int i = bx*256 + threadIdx.x;
    if (i < 256*516){
      int k = i / 516, n = i % 516;
      float v;
      if (n < 256) v = enc_w[(size_t)k*256 + n];
      else if (n < 514){
        int f2 = n - 256;
        float win = sqrtf(0.5f - 0.5f*cosf(PI2F * (float)k / 256.0f));
        int f = (f2 < NFREQ) ? f2 : (f2 - NFREQ);
        int m = (k * f) & 255;
        float th = PI2F * (float)m / 256.0f;
        v = (f2 < NFREQ) ? win * cosf(th) : -win * sinf(th);
      } else v = 0.f;
      bfr[i] = v;
      return;
    }
    int j = i - 256*516;
    if (j < 514*256){
      int k = j / 256, n = j & 255;
      float v;
      if (k < 256){
        v = 0.5f * dec_w[(size_t)k*256 + n];
      } else {
        int m = n & 63;
        float den = 0.f;
        #pragma unroll
        for (int q = 0; q < 4; q++) den += 0.5f - 0.5f*cosf(PI2F*(float)(m + 64*q)/256.0f);
        float win = sqrtf(0.5f - 0.5f*cosf(PI2F*(float)n/256.0f));
        float iw = win / den;
        int f = (k < 385) ? (k - 256) : (k - 385);
        int mm = (f * n) & 255;
        float th = PI2F * (float)mm / 256.0f;
        if (k < 385){
          float cf = (f==0 || f==128) ? 1.0f : 2.0f;
          v = 0.5f * iw * cf * cosf(th) * (1.0f/256.0f);
        } else {
          v = (f==0 || f==128) ? 0.0f : -1.0f * iw * sinf(th) * (1.0f/256.0f);
        }
      }
      decB[j] = v;
      return;
    }
    int jj = j - 514*256;
    if (jj < 256){ decBias[jj] = 0.5f * dec_b[jj]; return; }
    int n = jj - 256;
    if (n < 516) biasF[n] = (n < 256) ? enc_b[n] : 0.f;
    return;
  }
  if (bx < PREP_BLOCKS + PACKW_BLOCKS){
    size_t idx = (size_t)(bx - PREP_BLOCKS)*256 + threadIdx.x;
    const size_t PER = (size_t)32*131072;
    if (idx < PER){
      int i = (int)(idx >> 17);
      int o = (int)(idx & 131071);
      int kc = o >> 14;
      int n16 = (o >> 9) & 31;
      int l = (o >> 3) & 63;
      int j = o & 7;
      int k = kc*32 + (l>>4)*8 + j;
      int n = n16*16 + (l&15);
      w1p[idx] = f2bf(c1_w[((size_t)i*256 + k)*512 + n]);
    } else {
      size_t o2 = idx - PER;
      int i = (int)(o2 >> 17);
      int o = (int)(o2 & 131071);
      int kc = o >> 13;
      int n16 = (o >> 9) & 15;
      int l = (o >> 3) & 63;
      int j = o & 7;
      int k = kc*32 + (l>>4)*8 + j;
      int n = n16*16 + (l&15);
      w2p[o2] = f2bf(g2_g[(size_t)i*512 + k] * c2_w[((size_t)i*512 + k)*256 + n]);
    }
    return;
  }
  if (bx < PREP_BLOCKS + PACKW_BLOCKS + BIAS2_BLOCKS){
    // bias2 fold: block (layer i, k-slab ks); 8-way atomic accumulation
    int bi = bx - (PREP_BLOCKS + PACKW_BLOCKS);
    int i = bi >> 3, ks = bi & 7;
    int n = threadIdx.x;
    float s1 = 0.f, s2 = 0.f;
    for (int k = ks*64; k < ks*64 + 64; k++){
      float w = c2_w[((size_t)i*512 + k)*256 + n];
      s1 = fmaf(g2_b[(size_t)i*512 + k], w, s1);
      s2 = fmaf(g2_g[(size_t)i*512 + k], w, s2);
    }
    atomicAdd(&c1c2[(size_t)i*512 + n], s1);
    atomicAdd(&c1c2[(size_t)i*512 + 256 + n], s2);
    return;
  }
  // pack sep_w -> bf16 MFMA B-fragment layout, N padded 7700 -> 7744
  {
    size_t idx = (size_t)(bx - (PREP_BLOCKS + PACKW_BLOCKS + BIAS2_BLOCKS))*256 + threadIdx.x;
    int j = (int)(idx & 7);
    int l = (int)((idx >> 3) & 63);
    int rest = (int)(idx >> 9);
    int n16 = rest % SEPNT16;
    int kc = rest / SEPNT16;
    int k = kc*32 + (l>>4)*8 + j;
    int n = n16*16 + (l&15);
    w3p[idx] = (n < SEPN) ? f2bf(sep_w[(size_t)k*SEPN + n]) : (ushort)0;
  }
}

// ---------------- pipelined 64x64 GEMM (non-TCN) ----------------
template<int ALOAD>
__global__ __launch_bounds__(256, 2) void gemm3(
    const float* __restrict__ A, const float* __restrict__ Bm,
    const float* __restrict__ bias, float* __restrict__ C,
    int M, int N, int K, int lda, int ldb, int relu_cols)
{
  __shared__ float As[16][68];
  __shared__ float Bs[16][68];
  const int tid = threadIdx.x;
  const int tx = tid & 15, ty = tid >> 4;
  const int row0 = blockIdx.y*64, col0 = blockIdx.x*64;
  const int am = tid >> 2, ak = (tid & 3)*4;
  const int bk = tid >> 4, bn = (tid & 15)*4;
  const int arow = row0 + am;
  const bool aok = arow < M;
  const float* aptr = nullptr;
  const float* ap0 = nullptr; const float* ap1 = nullptr;
  if (ALOAD == 2){
    int r = aok ? arow : 0;
    int b = r / T_, t = r % T_;
    ap0 = A + ((size_t)b*2)*L_ + t*64;
    ap1 = ap0 + L_;
  } else {
    aptr = A + (size_t)(aok ? arow : 0)*lda;
  }
  const bool bfull = (col0 + 64 <= N);
  const int ksteps = (K+15) >> 4;

  float4 av, bv;

#define LOADA(ks_) { int k0 = (ks_) << 4; \
    av = make_float4(0.f,0.f,0.f,0.f); \
    if (aok){ \
      if (ALOAD == 2){ \
        float4 u = *(const float4*)(ap0 + k0 + ak); \
        float4 w = *(const float4*)(ap1 + k0 + ak); \
        av.x = u.x+w.x; av.y = u.y+w.y; av.z = u.z+w.z; av.w = u.w+w.w; \
      } else if (k0 + ak + 4 <= lda){ \
        av = *(const float4*)(aptr + k0 + ak); \
      } else { \
        float* pv = (float*)&av; \
        for (int j = 0; j < 4; j++){ int k = k0+ak+j; if (k < K) pv[j] = aptr[k]; } \
      } \
    } }

#define LOADB(ks_) { int k = ((ks_) << 4) + bk; \
    bv = make_float4(0.f,0.f,0.f,0.f); \
    if (k < K){ \
      if (bfull) bv = *(const float4*)(Bm + (size_t)k*ldb + col0 + bn); \
      else { float* pv = (float*)&bv; \
        for (int j = 0; j < 4; j++){ int c = col0+bn+j; if (c < N) pv[j] = Bm[(size_t)k*ldb + c]; } } } }

  float acc[4][4] = {};
  LOADA(0); LOADB(0);
  for (int ks = 0; ks < ksteps; ks++){
    As[ak+0][am] = av.x; As[ak+1][am] = av.y;
    As[ak+2][am] = av.z; As[ak+3][am] = av.w;
    *(float4*)&Bs[bk][bn] = bv;
    __syncthreads();
    if (ks + 1 < ksteps){ LOADA(ks+1); LOADB(ks+1); }
    #pragma unroll
    for (int kk = 0; kk < 16; kk++){
      float a4[4], b4[4];
      *(float4*)a4 = *(const float4*)&As[kk][ty*4];
      *(float4*)b4 = *(const float4*)&Bs[kk][tx*4];
      #pragma unroll
      for (int i = 0; i < 4; i++)
        #pragma unroll
        for (int j = 0; j < 4; j++) acc[i][j] = fmaf(a4[i], b4[j], acc[i][j]);
    }
    __syncthreads();
  }
#undef LOADA
#undef LOADB

  float bb4[4];
  #pragma unroll
  for (int j = 0; j < 4; j++){
    int c = col0 + tx*4 + j;
    bb4[j] = (bias && c < N) ? bias[c] : 0.f;
  }
  #pragma unroll
  for (int i = 0; i < 4; i++){
    int r_l = row0 + ty*4 + i;
    if (r_l >= M) continue;
    size_t r_g = (size_t)r_l;
    int c0 = col0 + tx*4;
    if (bfull){
      float4 o; float* po = (float*)&o;
      #pragma unroll
      for (int j = 0; j < 4; j++){
        float v = acc[i][j] + bb4[j];
        if (c0 + j < relu_cols) v = fmaxf(v, 0.f);
        po[j] = v;
      }
      *(float4*)(C + r_g*N + c0) = o;
    } else {
      #pragma unroll
      for (int j = 0; j < 4; j++){
        int c = c0 + j;
        if (c >= N) continue;
        float v = acc[i][j] + bb4[j];
        if (c < relu_cols) v = fmaxf(v, 0.f);
        C[r_g*N + c] = v;
      }
    }
  }
}

// ---------------- separator: bf16 MFMA GEMM, M=3976 N=7700(pad 7744) K=256 ---
__global__ __launch_bounds__(256, 2) void k_sep(
    const ushort* __restrict__ xb, const ushort* __restrict__ wp,
    const float* __restrict__ bias, float* __restrict__ C)
{
  int id = blockIdx.x;
  int xcd = id & 7, sub = id >> 3;
  const int q = SEPBLK/8, r = SEPBLK%8;   // 952, 7 — bijective chunked map
  int lin = (xcd < r ? xcd*(q+1) : r*(q+1) + (xcd - r)*q) + sub;
  int nb = lin/63, mt = lin%63;
  int tid = threadIdx.x;
  int wv = tid >> 6, l = tid & 63;
  int row0 = mt*64 + wv*16;
  int lm = l & 15, lq = l >> 4;
  int row = row0 + lm;
  int rclamp = (row < MTOT) ? row : (MTOT-1);
  int n0 = nb*64;
  const ushort* ap = xb + (size_t)rclamp*256;
  f32x4 acc[4] = {};
  #pragma unroll
  for (int kc = 0; kc < 8; kc++){
    bf16x8 a = *(const bf16x8*)(ap + kc*32 + lq*8);
    #pragma unroll
    for (int nt = 0; nt < 4; nt++){
      bf16x8 bfv = *(const bf16x8*)(wp + (((size_t)kc*SEPNT16 + (n0>>4) + nt)*64 + l)*8);
      acc[nt] = __builtin_amdgcn_mfma_f32_16x16x32_bf16(a, bfv, acc[nt], 0, 0, 0);
    }
  }
  #pragma unroll
  for (int nt = 0; nt < 4; nt++){
    int col = n0 + nt*16 + lm;
    if (col >= SEPN) continue;
    float bb = bias[col];
    #pragma unroll
    for (int r2 = 0; r2 < 4; r2++){
      int t = row0 + lq*4 + r2;
      if (t < MTOT) C[(size_t)t*SEPN + col] = acc[nt][r2] + bb;
    }
  }
}

// ---- per-batch barrier (64 blocks/group), same-XCD L2 protocol (R7) ----
__device__ __forceinline__ void pbar(unsigned* bar, int grp){
  __syncthreads();   // compiler emits s_waitcnt vmcnt(0) before s_barrier -> stores in L2
  if (threadIdx.x == 0){
    unsigned* g = bar + grp*64;
    unsigned gen = __hip_atomic_load(g+32, __ATOMIC_RELAXED, __HIP_MEMORY_SCOPE_AGENT);
    unsigned p = gen & 1u;
    unsigned a = __hip_atomic_fetch_add(g+p, 1u, __ATOMIC_RELAXED, __HIP_MEMORY_SCOPE_AGENT);
    if (a == 63u){
      __hip_atomic_store(g+p, 0u, __ATOMIC_RELAXED, __HIP_MEMORY_SCOPE_AGENT);
      __hip_atomic_store(g+32, gen+1u, __ATOMIC_RELAXED, __HIP_MEMORY_SCOPE_AGENT);
    } else {
      while (__hip_atomic_load(g+32, __ATOMIC_RELAXED, __HIP_MEMORY_SCOPE_AGENT) == gen)
        __builtin_amdgcn_s_sleep(1);
    }
    asm volatile("buffer_inv sc0" ::: "memory");
  }
  __syncthreads();
}

// ================= fused persistent TCN (normal launch, graph-safe) ========
// R13 = R11 (verified best): 512 blocks = 2/CU, nb 8-way (traffic sweet
// spot), LDS-staged per-channel constants (L1 dedup win), NT weight loads,
// per-batch barriers with same-XCD L2 protocol. R12's wave kc-split is
// reverted: it destroyed L2 weight reuse (FETCH 78MB->1.85GB) and added
// 11M LDS bank conflicts.
__global__ __launch_bounds__(256, 2) void k_tcn(
    float* __restrict__ x0, float* __restrict__ x1,
    float* __restrict__ Ubuf, ushort* __restrict__ yb,
    const ushort* __restrict__ w1pA, const ushort* __restrict__ w2pA,
    const float* __restrict__ c1bA, const float* __restrict__ p1A,
    const float* __restrict__ g1gA, const float* __restrict__ g1bA,
    const float* __restrict__ dwA, const float* __restrict__ p2A,
    const float* __restrict__ c2bA, const float* __restrict__ ccA,
    float* __restrict__ gsum, unsigned* bar)
{
  __shared__ float red[8];
  __shared__ float cst[3072];   // 12 KB: B: ga|ba|dw0|dw1|dw2|pa (6x512); A: addv (256)
  const int tid = threadIdx.x;
  const int wv = tid >> 6, l = tid & 63;
  const int bid = blockIdx.x;
  const int b = bid & 7, mt = (bid >> 3) & 7, nb = bid >> 6;
  const int row0 = mt*64 + wv*16;
  const int lm = l & 15, lq = l >> 4;
  const int row = row0 + lm;
  const bool rok = row < T_;
  const size_t rbase = ((size_t)b*T_ + row)*256;
  const float icnt = 1.f/((float)T_*(float)H_);

  for (int i = 0; i < NB; i++){
    // ---------------- phase A (k_ka body, LDS addv) ----------------
    {
      const float* xr = (i == 0) ? x0 : (((i-1)&1) ? x1 : x0);
      float* xw = (i & 1) ? x1 : x0;
      const ushort* w1p = w1pA + (size_t)i*131072;
      const float* bias = c1bA + (size_t)i*H_;
      const float* pa   = p1A + (size_t)i*H_;
      float* gs = gsum + i*32;
      const int hasU = (i > 0) ? 1 : 0;
      const float* c2bPrev = c2bA + (size_t)((i > 0) ? (i-1) : 0)*BTL;
      const float* ccPrev  = ccA  + (size_t)((i > 0) ? (i-1) : 0)*512;
      const float* gsPrev  = (i == 0) ? gsum : (gsum + (i-1)*32 + 16);

      float rstd2 = 0.f;
      if (hasU){
        float m2 = aldf(gsPrev + b*2)*icnt;
        rstd2 = rsqrtf(aldf(gsPrev + b*2 + 1)*icnt - m2*m2 + MEPS);
        float mr = m2*rstd2;
        // stage folded residual add: addv[c] = c2b[c] + cc1[c] - mr*cc2[c]
        cst[tid] = c2bPrev[tid] + ccPrev[tid] - mr*ccPrev[256 + tid];
      }
      __syncthreads();
      int n0 = nb*64;
      f32x4 acc[4] = {};
      #pragma unroll 4
      for (int kc = 0; kc < 8; kc++){
        int k0 = kc*32 + lq*8;
        float xv[8];
        *(float4*)&xv[0] = *(const float4*)(xr + rbase + k0);
        *(float4*)&xv[4] = *(const float4*)(xr + rbase + k0 + 4);
        if (hasU){
          float uv[8], av8[8];
          *(float4*)&uv[0]  = *(const float4*)(Ubuf + rbase + k0);
          *(float4*)&uv[4]  = *(const float4*)(Ubuf + rbase + k0 + 4);
          *(float4*)&av8[0] = *(float4*)&cst[k0];
          *(float4*)&av8[4] = *(float4*)&cst[k0 + 4];
          #pragma unroll
          for (int j = 0; j < 8; j++)
            xv[j] = xv[j] + rstd2*uv[j] + av8[j];
          if (nb == 0 && rok){
            *(float4*)(xw + rbase + k0)     = *(float4*)&xv[0];
            *(float4*)(xw + rbase + k0 + 4) = *(float4*)&xv[4];
          }
        }
        bf16x8 a;
        #pragma unroll
        for (int j = 0; j < 8; j++) a[j] = (short)f2bf(xv[j]);
        #pragma unroll
        for (int nt = 0; nt < 4; nt++){
          bf16x8 bf = __builtin_nontemporal_load(
              (const bf16x8*)(w1p + (((size_t)kc*32 + (n0>>4) + nt)*64 + l)*8));
          acc[nt] = __builtin_amdgcn_mfma_f32_16x16x32_bf16(a, bf, acc[nt], 0, 0, 0);
        }
      }
      float ps = 0.f, pss = 0.f;
      #pragma unroll
      for (int nt = 0; nt < 4; nt++){
        int col = n0 + nt*16 + lm;
        float bb = bias[col], pav = pa[col];
        #pragma unroll
        for (int r = 0; r < 4; r++){
          int t = row0 + lq*4 + r;
          if (t < T_){
            float v = acc[nt][r] + bb;
            float p = fmaxf(v, 0.f) + pav*fminf(v, 0.f);
            yb[((size_t)b*T_ + t)*512 + col] = f2bf(p);
            ps += p; pss += p*p;
          }
        }
      }
      #pragma unroll
      for (int off = 32; off > 0; off >>= 1){
        ps  += __shfl_down(ps, off);
        pss += __shfl_down(pss, off);
      }
      if (l == 0){ red[wv*2] = ps; red[wv*2+1] = pss; }
      __syncthreads();
      if (tid == 0) atomicAdd(&gs[b*2],   red[0]+red[2]+red[4]+red[6]);
      if (tid == 1) atomicAdd(&gs[b*2+1], red[1]+red[3]+red[5]+red[7]);
    }
    pbar(bar, b);
    // ---------------- phase B (k_kb body, LDS constants) ----------------
    {
      const int dil = 1 << (i & 7);
      const ushort* w2p = w2pA + (size_t)i*131072;
      const float* dwk = dwA + (size_t)i*3*H_;
      const float* gg  = g1gA + (size_t)i*H_;
      const float* gb  = g1bA + (size_t)i*H_;
      const float* pa  = p2A + (size_t)i*H_;
      const float* gs1 = gsum + i*32;
      float* gs2 = gsum + i*32 + 16;

      float m1 = aldf(gs1 + b*2)*icnt;
      float rstd1 = rsqrtf(aldf(gs1 + b*2 + 1)*icnt - m1*m1 + MEPS);
      // stage folded constants: ga | ba | dw0 | dw1 | dw2 | pa  (6 x 512)
      #pragma unroll
      for (int qq = 0; qq < 2; qq++){
        int c = tid + qq*256;
        float ga_ = gg[c]*rstd1;
        cst[c]        = ga_;
        cst[512 + c]  = gb[c] - m1*ga_;
        cst[1024 + c] = dwk[c];
        cst[1536 + c] = dwk[H_ + c];
        cst[2048 + c] = dwk[2*H_ + c];
        cst[2560 + c] = pa[c];
      }
      __syncthreads();
      int n0 = nb*32;
      f32x4 acc[2] = {};
      float sp = 0.f, spp = 0.f;
      const bool dostat = (nb == 0) && rok;
      #pragma unroll 4
      for (int kc = 0; kc < 16; kc++){
        int ch0 = kc*32 + lq*8;
        float ga8[8], ba8[8];
        *(float4*)&ga8[0] = *(float4*)&cst[ch0];
        *(float4*)&ga8[4] = *(float4*)&cst[ch0 + 4];
        *(float4*)&ba8[0] = *(float4*)&cst[512 + ch0];
        *(float4*)&ba8[4] = *(float4*)&cst[512 + ch0 + 4];
        float z[8] = {0.f,0.f,0.f,0.f,0.f,0.f,0.f,0.f};
        #pragma unroll
        for (int kk = 0; kk < 3; kk++){
          int tt = row + (kk-1)*dil;
          if (tt >= 0 && tt < T_){
            bf16x8 yv = *(const bf16x8*)(yb + ((size_t)b*T_ + tt)*512 + ch0);
            float d8[8];
            *(float4*)&d8[0] = *(float4*)&cst[1024 + kk*512 + ch0];
            *(float4*)&d8[4] = *(float4*)&cst[1024 + kk*512 + ch0 + 4];
            #pragma unroll
            for (int j = 0; j < 8; j++)
              z[j] = fmaf(d8[j], bf2f((ushort)yv[j])*ga8[j] + ba8[j], z[j]);
          }
        }
        float pa8[8];
        *(float4*)&pa8[0] = *(float4*)&cst[2560 + ch0];
        *(float4*)&pa8[4] = *(float4*)&cst[2560 + ch0 + 4];
        bf16x8 a;
        #pragma unroll
        for (int j = 0; j < 8; j++){
          float p = fmaxf(z[j], 0.f) + pa8[j]*fminf(z[j], 0.f);
          if (dostat){ sp += p; spp += p*p; }
          a[j] = (short)f2bf(p);
        }
        #pragma unroll
        for (int nt = 0; nt < 2; nt++){
          bf16x8 bf = __builtin_nontemporal_load(
              (const bf16x8*)(w2p + (((size_t)kc*16 + (n0>>4) + nt)*64 + l)*8));
          acc[nt] = __builtin_amdgcn_mfma_f32_16x16x32_bf16(a, bf, acc[nt], 0, 0, 0);
        }
      }
      #pragma unroll
      for (int nt = 0; nt < 2; nt++){
        int col = n0 + nt*16 + lm;
        #pragma unroll
        for (int r = 0; r < 4; r++){
          int tr = row0 + lq*4 + r;
          if (tr < T_) Ubuf[((size_t)b*T_ + tr)*256 + col] = acc[nt][r];
        }
      }
      if (nb == 0){
        #pragma unroll
        for (int off = 32; off > 0; off >>= 1){
          sp  += __shfl_down(sp, off);
          spp += __shfl_down(spp, off);
        }
        if (l == 0){ red[wv*2] = sp; red[wv*2+1] = spp; }
        __syncthreads();
        if (tid == 0) atomicAdd(&gs2[b*2],   red[0]+red[2]+red[4]+red[6]);
        if (tid == 1) atomicAdd(&gs2[b*2+1], red[1]+red[3]+red[5]+red[7]);
      }
    }
    if (i < NB-1) pbar(bar, b);
  }
}

// final deferred apply after layer 31 — writes x_final directly as bf16
__global__ __launch_bounds__(256) void k_applyx(
    const float* __restrict__ xr, const float* __restrict__ U,
    const float* __restrict__ gs, const float* __restrict__ c2b,
    const float* __restrict__ cc, ushort* __restrict__ xo)
{
  int i = blockIdx.x*256 + threadIdx.x;
  if (i < B_*T_*256){
    int b = i / (T_*256);
    int k = i & 255;
    const float icnt = 1.f/((float)T_*(float)H_);
    float m = gs[b*2]*icnt;
    float rstd = rsqrtf(gs[b*2+1]*icnt - m*m + MEPS);
    float mr = m*rstd;
    xo[i] = f2bf(xr[i] + rstd*U[i] + c2b[k] + cc[k] - mr*cc[256 + k]);
  }
}

// ---------------- cLN over [enc | log1p(mag)] ----------------
__global__ __launch_bounds__(256) void k_cln(
    const float* __restrict__ cf,
    const float* __restrict__ gamma, const float* __restrict__ beta,
    float* __restrict__ mag, float* __restrict__ cosp, float* __restrict__ sinp,
    float* __restrict__ xln){
  int t = blockIdx.x, b = blockIdx.y, tid = threadIdx.x;
  size_t row = (size_t)b*T_ + t;
  __shared__ float feat[FC];
  __shared__ float red[8];
  feat[tid] = cf[row*FRSTR + tid];
  if (tid < NFREQ){
    float re = cf[row*FRSTR + 256 + tid], im = cf[row*FRSTR + 385 + tid];
    float m = sqrtf(re*re + im*im);
    mag[row*NFREQ + tid] = m;
    float c = 1.f, s = 0.f;
    if (m > 0.f){ c = re/m; s = im/m; }
    cosp[row*NFREQ + tid] = c;
    sinp[row*NFREQ + tid] = s;
    feat[AE + tid] = log1pf(m);
  }
  __syncthreads();
  float v = feat[tid] + ((tid < FC-256) ? feat[256+tid] : 0.f);
  #pragma unroll
  for (int off = 32; off > 0; off >>= 1) v += __shfl_down(v, off);
  if ((tid & 63) == 0) red[tid>>6] = v;
  __syncthreads();
  float mean = (red[0]+red[1]+red[2]+red[3]) * (1.0f/FC);
  float d0 = feat[tid] - mean;
  float vv = d0*d0;
  if (tid < FC-256){ float d1 = feat[256+tid] - mean; vv += d1*d1; }
  __syncthreads();
  #pragma unroll
  for (int off = 32; off > 0; off >>= 1) vv += __shfl_down(vv, off);
  if ((tid & 63) == 0) red[tid>>6] = vv;
  __syncthreads();
  float var = (red[0]+red[1]+red[2]+red[3]) * (1.0f/FC);
  float rstd = rsqrtf(var + MEPS);
  xln[row*XSTR + tid] = (feat[tid]-mean)*rstd*gamma[tid] + beta[tid];
  if (tid < FC-256)
    xln[row*XSTR + 256+tid] = (feat[256+tid]-mean)*rstd*gamma[256+tid] + beta[256+tid];
  if (tid < XSTR-FC) xln[row*XSTR + FC + tid] = 0.f;
}

// ---------------- attractor accumulation ------------
#define ATTR_CH 16
__global__ __launch_bounds__(256) void k_attr2(const float* __restrict__ emb,
                                               const float* __restrict__ anchors,
                                               float* __restrict__ acc){
  const int c0a[16] = {0,0,0,0,0,1,1,1,1,2,2,2,3,3,4,0};
  const int c1a[16] = {1,2,3,4,5,2,3,4,5,3,4,5,4,5,5,0};
  int by = blockIdx.y;
  int b = by >> 2, g = by & 3;
  int tid = threadIdx.x;
  __shared__ float anc[6][20];
  __shared__ float wred[4][84];
  if (tid < 120) anc[tid/20][tid%20] = anchors[tid];
  __syncthreads();
  float ar[4][21];
  #pragma unroll
  for (int q = 0; q < 4; q++)
    #pragma unroll
    for (int e = 0; e < 21; e++) ar[q][e] = 0.f;
  const float* eb = emb + (size_t)b*KB*EMBED;
  for (int k = blockIdx.x*256 + tid; k < KB; k += ATTR_CH*256){
    float e[20];
    const float4* p = (const float4*)(eb + (size_t)k*EMBED);
    #pragma unroll
    for (int i = 0; i < 5; i++){
      float4 v = p[i];
      e[4*i] = v.x; e[4*i+1] = v.y; e[4*i+2] = v.z; e[4*i+3] = v.w;
    }
    float d[6];
    #pragma unroll
    for (int c = 0; c < 6; c++){
      float s = 0.f;
      #pragma unroll
      for (int j = 0; j < 20; j++) s = fmaf(e[j], anc[c][j], s);
      d[c] = s;
    }
    #pragma unroll
    for (int q = 0; q < 4; q++){
      int s = g*4 + q;
      float w = (s == 15) ? 1.0f : 1.0f / (1.0f + expf(d[c1a[s]] - d[c0a[s]]));
      #pragma unroll
      for (int j = 0; j < 20; j++) ar[q][j] = fmaf(w, e[j], ar[q][j]);
      ar[q][20] += w;
    }
  }
  #pragma unroll
  for (int q = 0; q < 4; q++)
    #pragma unroll
    for (int e = 0; e < 21; e++)
      #pragma unroll
      for (int off = 32; off > 0; off >>= 1)
        ar[q][e] += __shfl_down(ar[q][e], off);
  if ((tid & 63) == 0){
    int w = tid >> 6;
    #pragma unroll
    for (int q = 0; q < 4; q++)
      #pragma unroll
      for (int e = 0; e < 21; e++) wred[w][q*21+e] = ar[q][e];
  }
  __syncthreads();
  if (tid < 84){
    float s = wred[0][tid] + wred[1][tid] + wred[2][tid] + wred[3][tid];
    int q = tid / 21, e = tid % 21;
    atomicAdd(&acc[((size_t)b*16 + g*4 + q)*21 + e], s);
  }
}

// ---------------- attractor normalize + select ----------------
__global__ __launch_bounds__(128) void k_attrfin2(const float* __restrict__ acc,
                                                  float* __restrict__ attractors){
  __shared__ float aN[120][40];
  __shared__ float sp[120];
  int tid = threadIdx.x;
  if (tid < 120){
    int b = tid / 15, p = tid % 15;
    const float* ap = acc + ((size_t)b*16 + p)*21;
    const float* ae = acc + ((size_t)b*16 + 15)*21;
    float den0 = ap[20];
    float den1 = (float)KB - den0;
    float s = 0.f;
    for (int e = 0; e < 20; e++){
      float a0 = ap[e] / den0;
      float a1 = (ae[e] - ap[e]) / den1;
      aN[tid][e] = a0; aN[tid][20+e] = a1;
      s = fmaf(a0, a1, s);
    }
    sp[tid] = s;
  }
  __syncthreads();
  if (tid < B_){
    int base = tid * 15, best = 0;
    float bv = sp[base];
    for (int p = 1; p < 15; p++) if (sp[base+p] < bv){ bv = sp[base+p]; best = p; }
    for (int i = 0; i < 40; i++) attractors[tid*40 + i] = aN[base+best][i];
  }
}

// ---------------- build decoder-GEMM A rows (stride 516, pads zeroed) -------
__global__ __launch_bounds__(256) void k_afull(
    const float* __restrict__ emb, const float* __restrict__ cf,
    const float* __restrict__ mag, const float* __restrict__ cosp,
    const float* __restrict__ sinp, const float* __restrict__ attractors,
    float* __restrict__ Af){
  int t = blockIdx.x, b = blockIdx.y, tid = threadIdx.x;
  __shared__ float att[40];
  if (tid < 40) att[tid] = attractors[b*40 + tid];
  __syncthreads();
  size_t row = (size_t)b*T_ + t;
  size_t r0 = ((size_t)(b*2+0)*T_ + t)*AFSTR;
  size_t r1 = ((size_t)(b*2+1)*T_ + t)*AFSTR;
  for (int f = tid; f < FC; f += 256){
    const float* e = emb + (row*FC + f)*20;
    float l0 = 0.f, l1 = 0.f;
    #pragma unroll
    for (int j = 0; j < 20; j++){
      float ev = e[j];
      l0 = fmaf(ev, att[j],    l0);
      l1 = fmaf(ev, att[20+j], l1);
    }
    if (f < AE){
      float ft = cf[row*FRSTR + f];
      Af[r0 + f] = l0*ft;
      Af[r1 + f] = l1*ft;
    } else {
      int fi = f - AE;
      float ft = mag[row*NFREQ + fi];
      float c = cosp[row*NFREQ + fi], s = sinp[row*NFREQ + fi];
      float s0 = l0*ft, s1v = l1*ft;
      Af[r0 + 256 + fi] = c*s0;  Af[r0 + 385 + fi] = s*s0;
      Af[r1 + 256 + fi] = c*s1v; Af[r1 + 385 + fi] = s*s1v;
    }
  }
  if (tid < 2){
    Af[r0 + 514 + tid] = 0.f;
    Af[r1 + 514 + tid] = 0.f;
  }
}

// ---------------- overlap-add gather ----------------
__global__ __launch_bounds__(256) void k_ola(const float* __restrict__ frames,
                                             float* __restrict__ out){
  int i = blockIdx.x*256 + threadIdx.x;
  if (i < B_*2*L_){
    int bs = i / L_, l = i % L_;
    int t0 = l >> 6;
    float s = 0.f;
    #pragma unroll
    for (int j = 0; j < 4; j++){
      int t = t0 - j;
      if (t >= 0 && t < T_){
        int k = l - t*64;
        s += frames[((size_t)bs*T_ + t)*256 + k];
      }
    }
    out[i] = s;
  }
}

// ---------------- launcher ----------------
extern "C" void kernel_launch(void* const* d_in, const int* in_sizes, int n_in,
                              void* d_out, int out_size, void* d_ws, size_t ws_size,
                              hipStream_t stream) {
  const float* audios   = (const float*)d_in[0];
  const float* enc_w    = (const float*)d_in[1];
  const float* enc_b    = (const float*)d_in[2];
  const float* bgamma   = (const float*)d_in[3];
  const float* bbeta    = (const float*)d_in[4];
  const float* bottle_w = (const float*)d_in[5];
  const float* bottle_b = (const float*)d_in[6];
  const float* c1_w     = (const float*)d_in[7];
  const float* c1_b     = (const float*)d_in[8];
  const float* p1       = (const float*)d_in[9];
  const float* g1_g     = (const float*)d_in[10];
  const float* g1_b     = (const float*)d_in[11];
  const float* dwp      = (const float*)d_in[12];
  const float* p2       = (const float*)d_in[13];
  const float* g2_g     = (const float*)d_in[14];
  const float* g2_b     = (const float*)d_in[15];
  const float* c2_w     = (const float*)d_in[16];
  const float* c2_b     = (const float*)d_in[17];
  const float* sep_w    = (const float*)d_in[18];
  const float* sep_b    = (const float*)d_in[19];
  const float* anchors  = (const float*)d_in[20];
  const float* dec_w    = (const float*)d_in[21];
  const float* dec_b    = (const float*)d_in[22];

  float* ws = (float*)d_ws;
  float* bfr   = ws + o_bfr;
  float* decB  = ws + o_decB;
  float* decBias = ws + o_decBias;
  float* biasF = ws + o_biasF;
  float* cf    = ws + o_cf;
  float* mag   = ws + o_mag;
  float* cosp  = ws + o_cosp;
  float* sinp  = ws + o_sinp;
  float* xln   = ws + o_xln;
  float* xbuf0 = ws + o_x;
  float* xbuf1 = ws + o_y;                         // first half of o_y region
  float* Ubuf  = ws + o_y + (size_t)B_*T_*BTL;     // second half
  float* gsum  = ws + o_gsum;
  float* accp  = ws + o_acc;
  float* attp  = ws + o_att;
  float* embp  = ws + o_emb;
  float* Afull = ws + o_Af;
  float* framesp = ws + o_fr;
  float* c1c2  = ws + o_c1c2;
  unsigned* barp = (unsigned*)(ws + o_bar);
  ushort* w1p  = (ushort*)(ws + o_w1p);
  ushort* w2p  = (ushort*)(ws + o_w2p);
  ushort* w3p  = (ushort*)(ws + o_Af);   // packed sep_w bf16; dead before k_afull writes Af
  ushort* xb16 = (ushort*)(ws + o_xln);  // bf16 x_final; xln dead after bottleneck GEMM
  ushort* yb16 = (ushort*)(ws + o_z);

  // zero atomic accumulators (gsum 1024 + attr acc 2688, contiguous), c1c2, barrier
  hipMemsetAsync((void*)gsum, 0, (1024 + (size_t)B_*16*21) * sizeof(float), stream);
  hipMemsetAsync((void*)c1c2, 0, (size_t)32*512*sizeof(float), stream);
  hipMemsetAsync((void*)barp, 0, 1024*sizeof(float), stream);

  k_setup<<<PREP_BLOCKS + PACKW_BLOCKS + BIAS2_BLOCKS + PACKSEP_BLOCKS, 256, 0, stream>>>(
      enc_w, enc_b, dec_w, dec_b, c1_w, c2_w, g2_g, g2_b, sep_w,
      bfr, decB, decBias, biasF, w1p, w2p, c1c2, w3p);

  // frames GEMM: mix-on-load, [enc | spec] out, M=3976, N=516, K=256
  gemm3<2><<<dim3(9, 63), 256, 0, stream>>>(
      audios, bfr, biasF, cf, B_*T_, FRSTR, 256, 0, FRSTR, 256);

  k_cln<<<dim3(T_, B_), 256, 0, stream>>>(cf, bgamma, bbeta, mag, cosp, sinp, xln);

  // bottleneck -> x(0) in buf0
  gemm3<0><<<dim3(4, 63), 256, 0, stream>>>(
      xln, bottle_w, bottle_b, xbuf0, B_*T_, BTL, FC, XSTR, BTL, 0);

  // TCN: single persistent kernel, per-batch barriers, LDS-staged constants
  k_tcn<<<dim3(512), dim3(256), 0, stream>>>(
      xbuf0, xbuf1, Ubuf, yb16, w1p, w2p,
      c1_b, p1, g1_g, g1_b, dwp, p2, c2_b, c1c2, gsum, barp);

  // final apply: x_final = x(31) + rstd2*U(31) + cadd(31) -> bf16 xb16 (x(31) in buf1)
  k_applyx<<<(B_*T_*256 + 255)/256, 256, 0, stream>>>(
      xbuf1, Ubuf, gsum + (NB-1)*32 + 16,
      c2_b + (size_t)(NB-1)*BTL, c1c2 + (size_t)(NB-1)*512, xb16);

  // separator (bf16 MFMA): M=3976, N=7700 (pad 7744), K=256; XCD-chunked
  k_sep<<<dim3(SEPBLK), 256, 0, stream>>>(xb16, w3p, sep_b, embp);

  // attractors
  k_attr2<<<dim3(ATTR_CH, B_*4), 256, 0, stream>>>(embp, anchors, accp);
  k_attrfin2<<<1, 128, 0, stream>>>(accp, attp);

  // decode: M=7952, N=256, K=514 (lda=516, zero-padded)
  k_afull<<<dim3(T_, B_), 256, 0, stream>>>(embp, cf, mag, cosp, sinp, attp, Afull);
  gemm3<0><<<dim3(4, 125), 256, 0, stream>>>(
      Afull, decB, decBias, framesp, 2*B_*T_, 256, 514, AFSTR, BTL, 0);
  k_ola<<<(B_*2*L_ + 255)/256, 256, 0, stream>>>(framesp, (float*)d_out);
}

// Round 14
// 1563.373 us; speedup vs baseline: 1.6486x; 1.1197x over previous
//
#include <hip/hip_runtime.h>
#include <math.h>

#define B_ 8
#define S_ 2
#define L_ 32000
#define T_ 497
#define AE 256
#define NFREQ 129
#define FC 385
#define XSTR 388
#define FRSTR 516
#define AFSTR 516
#define BTL 256
#define H_ 512
#define NB 32
#define EMBED 20
#define KB (T_*FC)
#define MEPS 1e-12f
#define PI2F 6.28318530717958647692f
#define MTOT (B_*T_)
#define SEPN 7700
#define SEPNT16 484   /* ceil(7700/16)=482 -> pad to 484 so 64-col tiles (121) divide evenly */
#define SEPBLK 7623   /* 121*63 */

typedef __attribute__((ext_vector_type(8))) short bf16x8;
typedef __attribute__((ext_vector_type(4))) float f32x4;

__device__ __forceinline__ ushort f2bf(float f){
  union { float f; unsigned u; } x; x.f = f;
  unsigned r = x.u + 0x7FFFu + ((x.u >> 16) & 1u);
  return (ushort)(r >> 16);
}
__device__ __forceinline__ float bf2f(ushort h){
  union { unsigned u; float f; } x; x.u = ((unsigned)h) << 16;
  return x.f;
}

// atomic-point load (bypasses L1 and scalar cache; sees device-scope atomicAdd)
__device__ __forceinline__ float aldf(const float* p){
  return __hip_atomic_load(p, __ATOMIC_RELAXED, __HIP_MEMORY_SCOPE_AGENT);
}

// ---------------- workspace layout (float units) ----------------
static constexpr size_t ALGN(size_t x){ return (x + 63) & ~(size_t)63; }
static constexpr size_t o_bfr  = 0;                                   // 256*516
static constexpr size_t o_decB = ALGN(o_bfr + (size_t)256*516);       // 514*256
static constexpr size_t o_decBias = ALGN(o_decB + (size_t)514*256);   // 256
static constexpr size_t o_biasF  = ALGN(o_decBias + 256);             // 516
static constexpr size_t o_cf   = ALGN(o_biasF + 516);                 // 3976*516
static constexpr size_t o_mag  = ALGN(o_cf + (size_t)B_*T_*FRSTR);
static constexpr size_t o_cosp = ALGN(o_mag + (size_t)B_*T_*NFREQ);
static constexpr size_t o_sinp = ALGN(o_cosp + (size_t)B_*T_*NFREQ);
static constexpr size_t o_xln  = ALGN(o_sinp + (size_t)B_*T_*NFREQ); // xln; later xb16 (bf16 x_final)
static constexpr size_t o_x    = ALGN(o_xln + (size_t)B_*T_*XSTR);   // x buf0 (3976*256)
static constexpr size_t o_y    = ALGN(o_x + (size_t)B_*T_*BTL);      // x buf1 + U  (2*3976*256) ; later framesp
static constexpr size_t o_z    = ALGN(o_y + (size_t)B_*T_*H_);       // yb16 (bf16 3976*512 + pad)
static constexpr size_t o_gsum = ALGN(o_z + (size_t)B_*T_*H_);       // 32*32
static constexpr size_t o_acc  = o_gsum + 1024;                      // B*16*21
static constexpr size_t o_att  = ALGN(o_acc + (size_t)B_*16*21);
static constexpr size_t o_emb  = ALGN(o_att + (size_t)B_*2*EMBED);
static constexpr size_t o_Af   = ALGN(o_emb + (size_t)B_*KB*EMBED);  // 7952*516; earlier: packed sep_w bf16
static constexpr size_t o_w1p  = ALGN(o_Af + (size_t)2*B_*T_*AFSTR); // 32*131072 ush
static constexpr size_t o_w2p  = ALGN(o_w1p + (size_t)2097152);
static constexpr size_t o_c1c2 = ALGN(o_w2p + (size_t)2097152);      // 32*512
static constexpr size_t o_bar  = ALGN(o_c1c2 + (size_t)32*512);      // grid-barrier state (1024 f)
static constexpr size_t o_fr   = o_y;

#define PREP_BLOCKS 1034
#define PACKW_BLOCKS 32768
#define BIAS2_BLOCKS 256
#define PACKSEP_BLOCKS 7744   /* 8*484*64*8 / 256 */

// ---------------- merged setup: bases/biases + weight packing + bias2 fold ---
__global__ __launch_bounds__(256) void k_setup(
    const float* __restrict__ enc_w, const float* __restrict__ enc_b,
    const float* __restrict__ dec_w, const float* __restrict__ dec_b,
    const float* __restrict__ c1_w, const float* __restrict__ c2_w,
    const float* __restrict__ g2_g, const float* __restrict__ g2_b,
    const float* __restrict__ sep_w,
    float* __restrict__ bfr, float* __restrict__ decB,
    float* __restrict__ decBias, float* __restrict__ biasF,
    ushort* __restrict__ w1p, ushort* __restrict__ w2p,
    float* __restrict__ c1c2, ushort* __restrict__ w3p)
{
  int bx = blockIdx.x;
  if (bx < PREP_BLOCKS){
    int i = bx*256 + threadIdx.x;
    if (i < 256*516){
      int k = i / 516, n = i % 516;
      float v;
      if (n < 256) v = enc_w[(size_t)k*256 + n];
      else if (n < 514){
        int f2 = n - 256;
        float win = sqrtf(0.5f - 0.5f*cosf(PI2F * (float)k / 256.0f));
        int f = (f2 < NFREQ) ? f2 : (f2 - NFREQ);
        int m = (k * f) & 255;
        float th = PI2F * (float)m / 256.0f;
        v = (f2 < NFREQ) ? win * cosf(th) : -win * sinf(th);
      } else v = 0.f;
      bfr[i] = v;
      return;
    }
    int j = i - 256*516;
    if (j < 514*256){
      int k = j / 256, n = j & 255;
      float v;
      if (k < 256){
        v = 0.5f * dec_w[(size_t)k*256 + n];
      } else {
        int m = n & 63;
        float den = 0.f;
        #pragma unroll
        for (int q = 0; q < 4; q++) den += 0.5f - 0.5f*cosf(PI2F*(float)(m + 64*q)/256.0f);
        float win = sqrtf(0.5f - 0.5f*cosf(PI2F*(float)n/256.0f));
        float iw = win / den;
        int f = (k < 385) ? (k - 256) : (k - 385);
        int mm = (f * n) & 255;
        float th = PI2F * (float)mm / 256.0f;
        if (k < 385){
          float cf = (f==0 || f==128) ? 1.0f : 2.0f;
          v = 0.5f * iw * cf * cosf(th) * (1.0f/256.0f);
        } else {
          v = (f==0 || f==128) ? 0.0f : -1.0f * iw * sinf(th) * (1.0f/256.0f);
        }
      }
      decB[j] = v;
      return;
    }
    int jj = j - 514*256;
    if (jj < 256){ decBias[jj] = 0.5f * dec_b[jj]; return; }
    int n = jj - 256;
    if (n < 516) biasF[n] = (n < 256) ? enc_b[n] : 0.f;
    return;
  }
  if (bx < PREP_BLOCKS + PACKW_BLOCKS){
    size_t idx = (size_t)(bx - PREP_BLOCKS)*256 + threadIdx.x;
    const size_t PER = (size_t)32*131072;
    if (idx < PER){
      int i = (int)(idx >> 17);
      int o = (int)(idx & 131071);
      int kc = o >> 14;
      int n16 = (o >> 9) & 31;
      int l = (o >> 3) & 63;
      int j = o & 7;
      int k = kc*32 + (l>>4)*8 + j;
      int n = n16*16 + (l&15);
      w1p[idx] = f2bf(c1_w[((size_t)i*256 + k)*512 + n]);
    } else {
      size_t o2 = idx - PER;
      int i = (int)(o2 >> 17);
      int o = (int)(o2 & 131071);
      int kc = o >> 13;
      int n16 = (o >> 9) & 15;
      int l = (o >> 3) & 63;
      int j = o & 7;
      int k = kc*32 + (l>>4)*8 + j;
      int n = n16*16 + (l&15);
      w2p[o2] = f2bf(g2_g[(size_t)i*512 + k] * c2_w[((size_t)i*512 + k)*256 + n]);
    }
    return;
  }
  if (bx < PREP_BLOCKS + PACKW_BLOCKS + BIAS2_BLOCKS){
    // bias2 fold: block (layer i, k-slab ks); 8-way atomic accumulation
    int bi = bx - (PREP_BLOCKS + PACKW_BLOCKS);
    int i = bi >> 3, ks = bi & 7;
    int n = threadIdx.x;
    float s1 = 0.f, s2 = 0.f;
    for (int k = ks*64; k < ks*64 + 64; k++){
      float w = c2_w[((size_t)i*512 + k)*256 + n];
      s1 = fmaf(g2_b[(size_t)i*512 + k], w, s1);
      s2 = fmaf(g2_g[(size_t)i*512 + k], w, s2);
    }
    atomicAdd(&c1c2[(size_t)i*512 + n], s1);
    atomicAdd(&c1c2[(size_t)i*512 + 256 + n], s2);
    return;
  }
  // pack sep_w -> bf16 MFMA B-fragment layout, N padded 7700 -> 7744
  {
    size_t idx = (size_t)(bx - (PREP_BLOCKS + PACKW_BLOCKS + BIAS2_BLOCKS))*256 + threadIdx.x;
    int j = (int)(idx & 7);
    int l = (int)((idx >> 3) & 63);
    int rest = (int)(idx >> 9);
    int n16 = rest % SEPNT16;
    int kc = rest / SEPNT16;
    int k = kc*32 + (l>>4)*8 + j;
    int n = n16*16 + (l&15);
    w3p[idx] = (n < SEPN) ? f2bf(sep_w[(size_t)k*SEPN + n]) : (ushort)0;
  }
}

// ---------------- pipelined 64x64 GEMM (non-TCN) ----------------
template<int ALOAD>
__global__ __launch_bounds__(256, 2) void gemm3(
    const float* __restrict__ A, const float* __restrict__ Bm,
    const float* __restrict__ bias, float* __restrict__ C,
    int M, int N, int K, int lda, int ldb, int relu_cols)
{
  __shared__ float As[16][68];
  __shared__ float Bs[16][68];
  const int tid = threadIdx.x;
  const int tx = tid & 15, ty = tid >> 4;
  const int row0 = blockIdx.y*64, col0 = blockIdx.x*64;
  const int am = tid >> 2, ak = (tid & 3)*4;
  const int bk = tid >> 4, bn = (tid & 15)*4;
  const int arow = row0 + am;
  const bool aok = arow < M;
  const float* aptr = nullptr;
  const float* ap0 = nullptr; const float* ap1 = nullptr;
  if (ALOAD == 2){
    int r = aok ? arow : 0;
    int b = r / T_, t = r % T_;
    ap0 = A + ((size_t)b*2)*L_ + t*64;
    ap1 = ap0 + L_;
  } else {
    aptr = A + (size_t)(aok ? arow : 0)*lda;
  }
  const bool bfull = (col0 + 64 <= N);
  const int ksteps = (K+15) >> 4;

  float4 av, bv;

#define LOADA(ks_) { int k0 = (ks_) << 4; \
    av = make_float4(0.f,0.f,0.f,0.f); \
    if (aok){ \
      if (ALOAD == 2){ \
        float4 u = *(const float4*)(ap0 + k0 + ak); \
        float4 w = *(const float4*)(ap1 + k0 + ak); \
        av.x = u.x+w.x; av.y = u.y+w.y; av.z = u.z+w.z; av.w = u.w+w.w; \
      } else if (k0 + ak + 4 <= lda){ \
        av = *(const float4*)(aptr + k0 + ak); \
      } else { \
        float* pv = (float*)&av; \
        for (int j = 0; j < 4; j++){ int k = k0+ak+j; if (k < K) pv[j] = aptr[k]; } \
      } \
    } }

#define LOADB(ks_) { int k = ((ks_) << 4) + bk; \
    bv = make_float4(0.f,0.f,0.f,0.f); \
    if (k < K){ \
      if (bfull) bv = *(const float4*)(Bm + (size_t)k*ldb + col0 + bn); \
      else { float* pv = (float*)&bv; \
        for (int j = 0; j < 4; j++){ int c = col0+bn+j; if (c < N) pv[j] = Bm[(size_t)k*ldb + c]; } } } }

  float acc[4][4] = {};
  LOADA(0); LOADB(0);
  for (int ks = 0; ks < ksteps; ks++){
    As[ak+0][am] = av.x; As[ak+1][am] = av.y;
    As[ak+2][am] = av.z; As[ak+3][am] = av.w;
    *(float4*)&Bs[bk][bn] = bv;
    __syncthreads();
    if (ks + 1 < ksteps){ LOADA(ks+1); LOADB(ks+1); }
    #pragma unroll
    for (int kk = 0; kk < 16; kk++){
      float a4[4], b4[4];
      *(float4*)a4 = *(const float4*)&As[kk][ty*4];
      *(float4*)b4 = *(const float4*)&Bs[kk][tx*4];
      #pragma unroll
      for (int i = 0; i < 4; i++)
        #pragma unroll
        for (int j = 0; j < 4; j++) acc[i][j] = fmaf(a4[i], b4[j], acc[i][j]);
    }
    __syncthreads();
  }
#undef LOADA
#undef LOADB

  float bb4[4];
  #pragma unroll
  for (int j = 0; j < 4; j++){
    int c = col0 + tx*4 + j;
    bb4[j] = (bias && c < N) ? bias[c] : 0.f;
  }
  #pragma unroll
  for (int i = 0; i < 4; i++){
    int r_l = row0 + ty*4 + i;
    if (r_l >= M) continue;
    size_t r_g = (size_t)r_l;
    int c0 = col0 + tx*4;
    if (bfull){
      float4 o; float* po = (float*)&o;
      #pragma unroll
      for (int j = 0; j < 4; j++){
        float v = acc[i][j] + bb4[j];
        if (c0 + j < relu_cols) v = fmaxf(v, 0.f);
        po[j] = v;
      }
      *(float4*)(C + r_g*N + c0) = o;
    } else {
      #pragma unroll
      for (int j = 0; j < 4; j++){
        int c = c0 + j;
        if (c >= N) continue;
        float v = acc[i][j] + bb4[j];
        if (c < relu_cols) v = fmaxf(v, 0.f);
        C[r_g*N + c] = v;
      }
    }
  }
}

// ---------------- separator: bf16 MFMA GEMM, M=3976 N=7700(pad 7744) K=256 ---
__global__ __launch_bounds__(256, 2) void k_sep(
    const ushort* __restrict__ xb, const ushort* __restrict__ wp,
    const float* __restrict__ bias, float* __restrict__ C)
{
  int id = blockIdx.x;
  int xcd = id & 7, sub = id >> 3;
  const int q = SEPBLK/8, r = SEPBLK%8;   // 952, 7 — bijective chunked map
  int lin = (xcd < r ? xcd*(q+1) : r*(q+1) + (xcd - r)*q) + sub;
  int nb = lin/63, mt = lin%63;
  int tid = threadIdx.x;
  int wv = tid >> 6, l = tid & 63;
  int row0 = mt*64 + wv*16;
  int lm = l & 15, lq = l >> 4;
  int row = row0 + lm;
  int rclamp = (row < MTOT) ? row : (MTOT-1);
  int n0 = nb*64;
  const ushort* ap = xb + (size_t)rclamp*256;
  f32x4 acc[4] = {};
  #pragma unroll
  for (int kc = 0; kc < 8; kc++){
    bf16x8 a = *(const bf16x8*)(ap + kc*32 + lq*8);
    #pragma unroll
    for (int nt = 0; nt < 4; nt++){
      bf16x8 bfv = *(const bf16x8*)(wp + (((size_t)kc*SEPNT16 + (n0>>4) + nt)*64 + l)*8);
      acc[nt] = __builtin_amdgcn_mfma_f32_16x16x32_bf16(a, bfv, acc[nt], 0, 0, 0);
    }
  }
  #pragma unroll
  for (int nt = 0; nt < 4; nt++){
    int col = n0 + nt*16 + lm;
    if (col >= SEPN) continue;
    float bb = bias[col];
    #pragma unroll
    for (int r2 = 0; r2 < 4; r2++){
      int t = row0 + lq*4 + r2;
      if (t < MTOT) C[(size_t)t*SEPN + col] = acc[nt][r2] + bb;
    }
  }
}

// ---- per-batch barrier (64 blocks/group), same-XCD L2 protocol (R7) ----
__device__ __forceinline__ void pbar(unsigned* bar, int grp){
  __syncthreads();   // compiler emits s_waitcnt vmcnt(0) before s_barrier -> stores in L2
  if (threadIdx.x == 0){
    unsigned* g = bar + grp*64;
    unsigned gen = __hip_atomic_load(g+32, __ATOMIC_RELAXED, __HIP_MEMORY_SCOPE_AGENT);
    unsigned p = gen & 1u;
    unsigned a = __hip_atomic_fetch_add(g+p, 1u, __ATOMIC_RELAXED, __HIP_MEMORY_SCOPE_AGENT);
    if (a == 63u){
      __hip_atomic_store(g+p, 0u, __ATOMIC_RELAXED, __HIP_MEMORY_SCOPE_AGENT);
      __hip_atomic_store(g+32, gen+1u, __ATOMIC_RELAXED, __HIP_MEMORY_SCOPE_AGENT);
    } else {
      while (__hip_atomic_load(g+32, __ATOMIC_RELAXED, __HIP_MEMORY_SCOPE_AGENT) == gen)
        __builtin_amdgcn_s_sleep(1);
    }
    asm volatile("buffer_inv sc0" ::: "memory");
  }
  __syncthreads();
}

// ================= fused persistent TCN (normal launch, graph-safe) ========
// R14 = R11 + LDS weight staging. The MFMA weight-fragment index depends only
// on (kc, nt, l) — NOT on wave id — so the 4 waves of a block were issuing 4x
// redundant NT L2 loads (128 KB issued / 32 KB unique per phase). Stage the
// 32 KB slice into LDS once (each thread 8 chunks), read via ds_read_b128
// (contiguous 16B/lane, conflict-free). Same global address stream shape as
// R11 (read once/block) -> cross-block L2 reuse preserved (R12's mistake
// avoided). LDS: 12 KB cst + 32 KB wlds ~= 45 KB -> 2 blocks/CU still fit.
__global__ __launch_bounds__(256, 2) void k_tcn(
    float* __restrict__ x0, float* __restrict__ x1,
    float* __restrict__ Ubuf, ushort* __restrict__ yb,
    const ushort* __restrict__ w1pA, const ushort* __restrict__ w2pA,
    const float* __restrict__ c1bA, const float* __restrict__ p1A,
    const float* __restrict__ g1gA, const float* __restrict__ g1bA,
    const float* __restrict__ dwA, const float* __restrict__ p2A,
    const float* __restrict__ c2bA, const float* __restrict__ ccA,
    float* __restrict__ gsum, unsigned* bar)
{
  __shared__ float red[8];
  __shared__ float cst[3072];     // 12 KB: B: ga|ba|dw0|dw1|dw2|pa (6x512); A: addv (256)
  __shared__ ushort wlds[16384];  // 32 KB: per-phase weight slice (32 frags x 64 lanes x 8)
  const int tid = threadIdx.x;
  const int wv = tid >> 6, l = tid & 63;
  const int bid = blockIdx.x;
  const int b = bid & 7, mt = (bid >> 3) & 7, nb = bid >> 6;
  const int row0 = mt*64 + wv*16;
  const int lm = l & 15, lq = l >> 4;
  const int row = row0 + lm;
  const bool rok = row < T_;
  const size_t rbase = ((size_t)b*T_ + row)*256;
  const float icnt = 1.f/((float)T_*(float)H_);

  for (int i = 0; i < NB; i++){
    // ---------------- phase A (k_ka body, LDS addv + LDS weights) ----------
    {
      const float* xr = (i == 0) ? x0 : (((i-1)&1) ? x1 : x0);
      float* xw = (i & 1) ? x1 : x0;
      const ushort* w1p = w1pA + (size_t)i*131072;
      const float* bias = c1bA + (size_t)i*H_;
      const float* pa   = p1A + (size_t)i*H_;
      float* gs = gsum + i*32;
      const int hasU = (i > 0) ? 1 : 0;
      const float* c2bPrev = c2bA + (size_t)((i > 0) ? (i-1) : 0)*BTL;
      const float* ccPrev  = ccA  + (size_t)((i > 0) ? (i-1) : 0)*512;
      const float* gsPrev  = (i == 0) ? gsum : (gsum + (i-1)*32 + 16);

      int n0 = nb*64;
      // stage weight slice: frag f=(kc<<2)|nt, chunk c = f*64 + lane
      #pragma unroll
      for (int q = 0; q < 8; q++){
        int c = tid + q*256;
        int f = c >> 6, l2 = c & 63;
        int kcs = f >> 2, nts = f & 3;
        bf16x8 w = __builtin_nontemporal_load(
            (const bf16x8*)(w1p + (((size_t)kcs*32 + (n0>>4) + nts)*64 + l2)*8));
        *(bf16x8*)&wlds[(size_t)c*8] = w;
      }
      float rstd2 = 0.f;
      if (hasU){
        float m2 = aldf(gsPrev + b*2)*icnt;
        rstd2 = rsqrtf(aldf(gsPrev + b*2 + 1)*icnt - m2*m2 + MEPS);
        float mr = m2*rstd2;
        // stage folded residual add: addv[c] = c2b[c] + cc1[c] - mr*cc2[c]
        cst[tid] = c2bPrev[tid] + ccPrev[tid] - mr*ccPrev[256 + tid];
      }
      __syncthreads();
      f32x4 acc[4] = {};
      #pragma unroll 4
      for (int kc = 0; kc < 8; kc++){
        int k0 = kc*32 + lq*8;
        float xv[8];
        *(float4*)&xv[0] = *(const float4*)(xr + rbase + k0);
        *(float4*)&xv[4] = *(const float4*)(xr + rbase + k0 + 4);
        if (hasU){
          float uv[8], av8[8];
          *(float4*)&uv[0]  = *(const float4*)(Ubuf + rbase + k0);
          *(float4*)&uv[4]  = *(const float4*)(Ubuf + rbase + k0 + 4);
          *(float4*)&av8[0] = *(float4*)&cst[k0];
          *(float4*)&av8[4] = *(float4*)&cst[k0 + 4];
          #pragma unroll
          for (int j = 0; j < 8; j++)
            xv[j] = xv[j] + rstd2*uv[j] + av8[j];
          if (nb == 0 && rok){
            *(float4*)(xw + rbase + k0)     = *(float4*)&xv[0];
            *(float4*)(xw + rbase + k0 + 4) = *(float4*)&xv[4];
          }
        }
        bf16x8 a;
        #pragma unroll
        for (int j = 0; j < 8; j++) a[j] = (short)f2bf(xv[j]);
        #pragma unroll
        for (int nt = 0; nt < 4; nt++){
          bf16x8 bf = *(const bf16x8*)&wlds[(size_t)(((kc<<2) | nt)*64 + l)*8];
          acc[nt] = __builtin_amdgcn_mfma_f32_16x16x32_bf16(a, bf, acc[nt], 0, 0, 0);
        }
      }
      float ps = 0.f, pss = 0.f;
      #pragma unroll
      for (int nt = 0; nt < 4; nt++){
        int col = n0 + nt*16 + lm;
        float bb = bias[col], pav = pa[col];
        #pragma unroll
        for (int r = 0; r < 4; r++){
          int t = row0 + lq*4 + r;
          if (t < T_){
            float v = acc[nt][r] + bb;
            float p = fmaxf(v, 0.f) + pav*fminf(v, 0.f);
            yb[((size_t)b*T_ + t)*512 + col] = f2bf(p);
            ps += p; pss += p*p;
          }
        }
      }
      #pragma unroll
      for (int off = 32; off > 0; off >>= 1){
        ps  += __shfl_down(ps, off);
        pss += __shfl_down(pss, off);
      }
      if (l == 0){ red[wv*2] = ps; red[wv*2+1] = pss; }
      __syncthreads();
      if (tid == 0) atomicAdd(&gs[b*2],   red[0]+red[2]+red[4]+red[6]);
      if (tid == 1) atomicAdd(&gs[b*2+1], red[1]+red[3]+red[5]+red[7]);
    }
    pbar(bar, b);
    // ---------------- phase B (k_kb body, LDS constants + LDS weights) -----
    {
      const int dil = 1 << (i & 7);
      const ushort* w2p = w2pA + (size_t)i*131072;
      const float* dwk = dwA + (size_t)i*3*H_;
      const float* gg  = g1gA + (size_t)i*H_;
      const float* gb  = g1bA + (size_t)i*H_;
      const float* pa  = p2A + (size_t)i*H_;
      const float* gs1 = gsum + i*32;
      float* gs2 = gsum + i*32 + 16;

      int n0 = nb*32;
      // stage weight slice: frag f=(kc<<1)|nt, chunk c = f*64 + lane
      #pragma unroll
      for (int q = 0; q < 8; q++){
        int c = tid + q*256;
        int f = c >> 6, l2 = c & 63;
        int kcs = f >> 1, nts = f & 1;
        bf16x8 w = __builtin_nontemporal_load(
            (const bf16x8*)(w2p + (((size_t)kcs*16 + (n0>>4) + nts)*64 + l2)*8));
        *(bf16x8*)&wlds[(size_t)c*8] = w;
      }
      float m1 = aldf(gs1 + b*2)*icnt;
      float rstd1 = rsqrtf(aldf(gs1 + b*2 + 1)*icnt - m1*m1 + MEPS);
      // stage folded constants: ga | ba | dw0 | dw1 | dw2 | pa  (6 x 512)
      #pragma unroll
      for (int qq = 0; qq < 2; qq++){
        int c = tid + qq*256;
        float ga_ = gg[c]*rstd1;
        cst[c]        = ga_;
        cst[512 + c]  = gb[c] - m1*ga_;
        cst[1024 + c] = dwk[c];
        cst[1536 + c] = dwk[H_ + c];
        cst[2048 + c] = dwk[2*H_ + c];
        cst[2560 + c] = pa[c];
      }
      __syncthreads();
      f32x4 acc[2] = {};
      float sp = 0.f, spp = 0.f;
      const bool dostat = (nb == 0) && rok;
      #pragma unroll 4
      for (int kc = 0; kc < 16; kc++){
        int ch0 = kc*32 + lq*8;
        float ga8[8], ba8[8];
        *(float4*)&ga8[0] = *(float4*)&cst[ch0];
        *(float4*)&ga8[4] = *(float4*)&cst[ch0 + 4];
        *(float4*)&ba8[0] = *(float4*)&cst[512 + ch0];
        *(float4*)&ba8[4] = *(float4*)&cst[512 + ch0 + 4];
        float z[8] = {0.f,0.f,0.f,0.f,0.f,0.f,0.f,0.f};
        #pragma unroll
        for (int kk = 0; kk < 3; kk++){
          int tt = row + (kk-1)*dil;
          if (tt >= 0 && tt < T_){
            bf16x8 yv = *(const bf16x8*)(yb + ((size_t)b*T_ + tt)*512 + ch0);
            float d8[8];
            *(float4*)&d8[0] = *(float4*)&cst[1024 + kk*512 + ch0];
            *(float4*)&d8[4] = *(float4*)&cst[1024 + kk*512 + ch0 + 4];
            #pragma unroll
            for (int j = 0; j < 8; j++)
              z[j] = fmaf(d8[j], bf2f((ushort)yv[j])*ga8[j] + ba8[j], z[j]);
          }
        }
        float pa8[8];
        *(float4*)&pa8[0] = *(float4*)&cst[2560 + ch0];
        *(float4*)&pa8[4] = *(float4*)&cst[2560 + ch0 + 4];
        bf16x8 a;
        #pragma unroll
        for (int j = 0; j < 8; j++){
          float p = fmaxf(z[j], 0.f) + pa8[j]*fminf(z[j], 0.f);
          if (dostat){ sp += p; spp += p*p; }
          a[j] = (short)f2bf(p);
        }
        #pragma unroll
        for (int nt = 0; nt < 2; nt++){
          bf16x8 bf = *(const bf16x8*)&wlds[(size_t)(((kc<<1) | nt)*64 + l)*8];
          acc[nt] = __builtin_amdgcn_mfma_f32_16x16x32_bf16(a, bf, acc[nt], 0, 0, 0);
        }
      }
      #pragma unroll
      for (int nt = 0; nt < 2; nt++){
        int col = n0 + nt*16 + lm;
        #pragma unroll
        for (int r = 0; r < 4; r++){
          int tr = row0 + lq*4 + r;
          if (tr < T_) Ubuf[((size_t)b*T_ + tr)*256 + col] = acc[nt][r];
        }
      }
      if (nb == 0){
        #pragma unroll
        for (int off = 32; off > 0; off >>= 1){
          sp  += __shfl_down(sp, off);
          spp += __shfl_down(spp, off);
        }
        if (l == 0){ red[wv*2] = sp; red[wv*2+1] = spp; }
        __syncthreads();
        if (tid == 0) atomicAdd(&gs2[b*2],   red[0]+red[2]+red[4]+red[6]);
        if (tid == 1) atomicAdd(&gs2[b*2+1], red[1]+red[3]+red[5]+red[7]);
      }
    }
    if (i < NB-1) pbar(bar, b);
  }
}

// final deferred apply after layer 31 — writes x_final directly as bf16
__global__ __launch_bounds__(256) void k_applyx(
    const float* __restrict__ xr, const float* __restrict__ U,
    const float* __restrict__ gs, const float* __restrict__ c2b,
    const float* __restrict__ cc, ushort* __restrict__ xo)
{
  int i = blockIdx.x*256 + threadIdx.x;
  if (i < B_*T_*256){
    int b = i / (T_*256);
    int k = i & 255;
    const float icnt = 1.f/((float)T_*(float)H_);
    float m = gs[b*2]*icnt;
    float rstd = rsqrtf(gs[b*2+1]*icnt - m*m + MEPS);
    float mr = m*rstd;
    xo[i] = f2bf(xr[i] + rstd*U[i] + c2b[k] + cc[k] - mr*cc[256 + k]);
  }
}

// ---------------- cLN over [enc | log1p(mag)] ----------------
__global__ __launch_bounds__(256) void k_cln(
    const float* __restrict__ cf,
    const float* __restrict__ gamma, const float* __restrict__ beta,
    float* __restrict__ mag, float* __restrict__ cosp, float* __restrict__ sinp,
    float* __restrict__ xln){
  int t = blockIdx.x, b = blockIdx.y, tid = threadIdx.x;
  size_t row = (size_t)b*T_ + t;
  __shared__ float feat[FC];
  __shared__ float red[8];
  feat[tid] = cf[row*FRSTR + tid];
  if (tid < NFREQ){
    float re = cf[row*FRSTR + 256 + tid], im = cf[row*FRSTR + 385 + tid];
    float m = sqrtf(re*re + im*im);
    mag[row*NFREQ + tid] = m;
    float c = 1.f, s = 0.f;
    if (m > 0.f){ c = re/m; s = im/m; }
    cosp[row*NFREQ + tid] = c;
    sinp[row*NFREQ + tid] = s;
    feat[AE + tid] = log1pf(m);
  }
  __syncthreads();
  float v = feat[tid] + ((tid < FC-256) ? feat[256+tid] : 0.f);
  #pragma unroll
  for (int off = 32; off > 0; off >>= 1) v += __shfl_down(v, off);
  if ((tid & 63) == 0) red[tid>>6] = v;
  __syncthreads();
  float mean = (red[0]+red[1]+red[2]+red[3]) * (1.0f/FC);
  float d0 = feat[tid] - mean;
  float vv = d0*d0;
  if (tid < FC-256){ float d1 = feat[256+tid] - mean; vv += d1*d1; }
  __syncthreads();
  #pragma unroll
  for (int off = 32; off > 0; off >>= 1) vv += __shfl_down(vv, off);
  if ((tid & 63) == 0) red[tid>>6] = vv;
  __syncthreads();
  float var = (red[0]+red[1]+red[2]+red[3]) * (1.0f/FC);
  float rstd = rsqrtf(var + MEPS);
  xln[row*XSTR + tid] = (feat[tid]-mean)*rstd*gamma[tid] + beta[tid];
  if (tid < FC-256)
    xln[row*XSTR + 256+tid] = (feat[256+tid]-mean)*rstd*gamma[256+tid] + beta[256+tid];
  if (tid < XSTR-FC) xln[row*XSTR + FC + tid] = 0.f;
}

// ---------------- attractor accumulation ------------
#define ATTR_CH 16
__global__ __launch_bounds__(256) void k_attr2(const float* __restrict__ emb,
                                               const float* __restrict__ anchors,
                                               float* __restrict__ acc){
  const int c0a[16] = {0,0,0,0,0,1,1,1,1,2,2,2,3,3,4,0};
  const int c1a[16] = {1,2,3,4,5,2,3,4,5,3,4,5,4,5,5,0};
  int by = blockIdx.y;
  int b = by >> 2, g = by & 3;
  int tid = threadIdx.x;
  __shared__ float anc[6][20];
  __shared__ float wred[4][84];
  if (tid < 120) anc[tid/20][tid%20] = anchors[tid];
  __syncthreads();
  float ar[4][21];
  #pragma unroll
  for (int q = 0; q < 4; q++)
    #pragma unroll
    for (int e = 0; e < 21; e++) ar[q][e] = 0.f;
  const float* eb = emb + (size_t)b*KB*EMBED;
  for (int k = blockIdx.x*256 + tid; k < KB; k += ATTR_CH*256){
    float e[20];
    const float4* p = (const float4*)(eb + (size_t)k*EMBED);
    #pragma unroll
    for (int i = 0; i < 5; i++){
      float4 v = p[i];
      e[4*i] = v.x; e[4*i+1] = v.y; e[4*i+2] = v.z; e[4*i+3] = v.w;
    }
    float d[6];
    #pragma unroll
    for (int c = 0; c < 6; c++){
      float s = 0.f;
      #pragma unroll
      for (int j = 0; j < 20; j++) s = fmaf(e[j], anc[c][j], s);
      d[c] = s;
    }
    #pragma unroll
    for (int q = 0; q < 4; q++){
      int s = g*4 + q;
      float w = (s == 15) ? 1.0f : 1.0f / (1.0f + expf(d[c1a[s]] - d[c0a[s]]));
      #pragma unroll
      for (int j = 0; j < 20; j++) ar[q][j] = fmaf(w, e[j], ar[q][j]);
      ar[q][20] += w;
    }
  }
  #pragma unroll
  for (int q = 0; q < 4; q++)
    #pragma unroll
    for (int e = 0; e < 21; e++)
      #pragma unroll
      for (int off = 32; off > 0; off >>= 1)
        ar[q][e] += __shfl_down(ar[q][e], off);
  if ((tid & 63) == 0){
    int w = tid >> 6;
    #pragma unroll
    for (int q = 0; q < 4; q++)
      #pragma unroll
      for (int e = 0; e < 21; e++) wred[w][q*21+e] = ar[q][e];
  }
  __syncthreads();
  if (tid < 84){
    float s = wred[0][tid] + wred[1][tid] + wred[2][tid] + wred[3][tid];
    int q = tid / 21, e = tid % 21;
    atomicAdd(&acc[((size_t)b*16 + g*4 + q)*21 + e], s);
  }
}

// ---------------- attractor normalize + select ----------------
__global__ __launch_bounds__(128) void k_attrfin2(const float* __restrict__ acc,
                                                  float* __restrict__ attractors){
  __shared__ float aN[120][40];
  __shared__ float sp[120];
  int tid = threadIdx.x;
  if (tid < 120){
    int b = tid / 15, p = tid % 15;
    const float* ap = acc + ((size_t)b*16 + p)*21;
    const float* ae = acc + ((size_t)b*16 + 15)*21;
    float den0 = ap[20];
    float den1 = (float)KB - den0;
    float s = 0.f;
    for (int e = 0; e < 20; e++){
      float a0 = ap[e] / den0;
      float a1 = (ae[e] - ap[e]) / den1;
      aN[tid][e] = a0; aN[tid][20+e] = a1;
      s = fmaf(a0, a1, s);
    }
    sp[tid] = s;
  }
  __syncthreads();
  if (tid < B_){
    int base = tid * 15, best = 0;
    float bv = sp[base];
    for (int p = 1; p < 15; p++) if (sp[base+p] < bv){ bv = sp[base+p]; best = p; }
    for (int i = 0; i < 40; i++) attractors[tid*40 + i] = aN[base+best][i];
  }
}

// ---------------- build decoder-GEMM A rows (stride 516, pads zeroed) -------
__global__ __launch_bounds__(256) void k_afull(
    const float* __restrict__ emb, const float* __restrict__ cf,
    const float* __restrict__ mag, const float* __restrict__ cosp,
    const float* __restrict__ sinp, const float* __restrict__ attractors,
    float* __restrict__ Af){
  int t = blockIdx.x, b = blockIdx.y, tid = threadIdx.x;
  __shared__ float att[40];
  if (tid < 40) att[tid] = attractors[b*40 + tid];
  __syncthreads();
  size_t row = (size_t)b*T_ + t;
  size_t r0 = ((size_t)(b*2+0)*T_ + t)*AFSTR;
  size_t r1 = ((size_t)(b*2+1)*T_ + t)*AFSTR;
  for (int f = tid; f < FC; f += 256){
    const float* e = emb + (row*FC + f)*20;
    float l0 = 0.f, l1 = 0.f;
    #pragma unroll
    for (int j = 0; j < 20; j++){
      float ev = e[j];
      l0 = fmaf(ev, att[j],    l0);
      l1 = fmaf(ev, att[20+j], l1);
    }
    if (f < AE){
      float ft = cf[row*FRSTR + f];
      Af[r0 + f] = l0*ft;
      Af[r1 + f] = l1*ft;
    } else {
      int fi = f - AE;
      float ft = mag[row*NFREQ + fi];
      float c = cosp[row*NFREQ + fi], s = sinp[row*NFREQ + fi];
      float s0 = l0*ft, s1v = l1*ft;
      Af[r0 + 256 + fi] = c*s0;  Af[r0 + 385 + fi] = s*s0;
      Af[r1 + 256 + fi] = c*s1v; Af[r1 + 385 + fi] = s*s1v;
    }
  }
  if (tid < 2){
    Af[r0 + 514 + tid] = 0.f;
    Af[r1 + 514 + tid] = 0.f;
  }
}

// ---------------- overlap-add gather ----------------
__global__ __launch_bounds__(256) void k_ola(const float* __restrict__ frames,
                                             float* __restrict__ out){
  int i = blockIdx.x*256 + threadIdx.x;
  if (i < B_*2*L_){
    int bs = i / L_, l = i % L_;
    int t0 = l >> 6;
    float s = 0.f;
    #pragma unroll
    for (int j = 0; j < 4; j++){
      int t = t0 - j;
      if (t >= 0 && t < T_){
        int k = l - t*64;
        s += frames[((size_t)bs*T_ + t)*256 + k];
      }
    }
    out[i] = s;
  }
}

// ---------------- launcher ----------------
extern "C" void kernel_launch(void* const* d_in, const int* in_sizes, int n_in,
                              void* d_out, int out_size, void* d_ws, size_t ws_size,
                              hipStream_t stream) {
  const float* audios   = (const float*)d_in[0];
  const float* enc_w    = (const float*)d_in[1];
  const float* enc_b    = (const float*)d_in[2];
  const float* bgamma   = (const float*)d_in[3];
  const float* bbeta    = (const float*)d_in[4];
  const float* bottle_w = (const float*)d_in[5];
  const float* bottle_b = (const float*)d_in[6];
  const float* c1_w     = (const float*)d_in[7];
  const float* c1_b     = (const float*)d_in[8];
  const float* p1       = (const float*)d_in[9];
  const float* g1_g     = (const float*)d_in[10];
  const float* g1_b     = (const float*)d_in[11];
  const float* dwp      = (const float*)d_in[12];
  const float* p2       = (const float*)d_in[13];
  const float* g2_g     = (const float*)d_in[14];
  const float* g2_b     = (const float*)d_in[15];
  const float* c2_w     = (const float*)d_in[16];
  const float* c2_b     = (const float*)d_in[17];
  const float* sep_w    = (const float*)d_in[18];
  const float* sep_b    = (const float*)d_in[19];
  const float* anchors  = (const float*)d_in[20];
  const float* dec_w    = (const float*)d_in[21];
  const float* dec_b    = (const float*)d_in[22];

  float* ws = (float*)d_ws;
  float* bfr   = ws + o_bfr;
  float* decB  = ws + o_decB;
  float* decBias = ws + o_decBias;
  float* biasF = ws + o_biasF;
  float* cf    = ws + o_cf;
  float* mag   = ws + o_mag;
  float* cosp  = ws + o_cosp;
  float* sinp  = ws + o_sinp;
  float* xln   = ws + o_xln;
  float* xbuf0 = ws + o_x;
  float* xbuf1 = ws + o_y;                         // first half of o_y region
  float* Ubuf  = ws + o_y + (size_t)B_*T_*BTL;     // second half
  float* gsum  = ws + o_gsum;
  float* accp  = ws + o_acc;
  float* attp  = ws + o_att;
  float* embp  = ws + o_emb;
  float* Afull = ws + o_Af;
  float* framesp = ws + o_fr;
  float* c1c2  = ws + o_c1c2;
  unsigned* barp = (unsigned*)(ws + o_bar);
  ushort* w1p  = (ushort*)(ws + o_w1p);
  ushort* w2p  = (ushort*)(ws + o_w2p);
  ushort* w3p  = (ushort*)(ws + o_Af);   // packed sep_w bf16; dead before k_afull writes Af
  ushort* xb16 = (ushort*)(ws + o_xln);  // bf16 x_final; xln dead after bottleneck GEMM
  ushort* yb16 = (ushort*)(ws + o_z);

  // zero atomic accumulators (gsum 1024 + attr acc 2688, contiguous), c1c2, barrier
  hipMemsetAsync((void*)gsum, 0, (1024 + (size_t)B_*16*21) * sizeof(float), stream);
  hipMemsetAsync((void*)c1c2, 0, (size_t)32*512*sizeof(float), stream);
  hipMemsetAsync((void*)barp, 0, 1024*sizeof(float), stream);

  k_setup<<<PREP_BLOCKS + PACKW_BLOCKS + BIAS2_BLOCKS + PACKSEP_BLOCKS, 256, 0, stream>>>(
      enc_w, enc_b, dec_w, dec_b, c1_w, c2_w, g2_g, g2_b, sep_w,
      bfr, decB, decBias, biasF, w1p, w2p, c1c2, w3p);

  // frames GEMM: mix-on-load, [enc | spec] out, M=3976, N=516, K=256
  gemm3<2><<<dim3(9, 63), 256, 0, stream>>>(
      audios, bfr, biasF, cf, B_*T_, FRSTR, 256, 0, FRSTR, 256);

  k_cln<<<dim3(T_, B_), 256, 0, stream>>>(cf, bgamma, bbeta, mag, cosp, sinp, xln);

  // bottleneck -> x(0) in buf0
  gemm3<0><<<dim3(4, 63), 256, 0, stream>>>(
      xln, bottle_w, bottle_b, xbuf0, B_*T_, BTL, FC, XSTR, BTL, 0);

  // TCN: single persistent kernel, per-batch barriers, LDS constants+weights
  k_tcn<<<dim3(512), dim3(256), 0, stream>>>(
      xbuf0, xbuf1, Ubuf, yb16, w1p, w2p,
      c1_b, p1, g1_g, g1_b, dwp, p2, c2_b, c1c2, gsum, barp);

  // final apply: x_final = x(31) + rstd2*U(31) + cadd(31) -> bf16 xb16 (x(31) in buf1)
  k_applyx<<<(B_*T_*256 + 255)/256, 256, 0, stream>>>(
      xbuf1, Ubuf, gsum + (NB-1)*32 + 16,
      c2_b + (size_t)(NB-1)*BTL, c1c2 + (size_t)(NB-1)*512, xb16);

  // separator (bf16 MFMA): M=3976, N=7700 (pad 7744), K=256; XCD-chunked
  k_sep<<<dim3(SEPBLK), 256, 0, stream>>>(xb16, w3p, sep_b, embp);

  // attractors
  k_attr2<<<dim3(ATTR_CH, B_*4), 256, 0, stream>>>(embp, anchors, accp);
  k_attrfin2<<<1, 128, 0, stream>>>(accp, attp);

  // decode: M=7952, N=256, K=514 (lda=516, zero-padded)
  k_afull<<<dim3(T_, B_), 256, 0, stream>>>(embp, cf, mag, cosp, sinp, attp, Afull);
  gemm3<0><<<dim3(4, 125), 256, 0, stream>>>(
      Afull, decB, decBias, framesp, 2*B_*T_, 256, 514, AFSTR, BTL, 0);
  k_ola<<<(B_*2*L_ + 255)/256, 256, 0, stream>>>(framesp, (float*)d_out);
}